// Round 1
// baseline (1296.930 us; speedup 1.0000x reference)
//
#include <hip/hip_runtime.h>

// RWKV6Attention forward, fp32 correctness-first baseline.
// Pipeline: kA (shift+lerp+tanh+mix -> 5 mixed planes) -> kB (concat GEMM ->
// r|wpre|k|v|g) -> kC (w-LoRA up + -exp) -> kD1 (per-chunk rwkv6 local) ->
// kD2 (inter-chunk state scan, in-place) -> kD3 (o_inter = qe @ S_before) ->
// kE (GroupNorm + swish gate) -> kF (output GEMM).

#define DEVI __device__ __forceinline__

namespace {

constexpr int Bc   = 2;
constexpr int Lc   = 2048;
constexpr int Tc   = 4096;   // B*L
constexpr int HIDc = 1024;
constexpr int NHc  = 4;
constexpr int DKc  = 128;
constexpr int DVc  = 256;
constexpr int NCHc = 64;     // chunks of 32 per (b,h)

// workspace byte offsets (xm region reused after kB for wfin/qe/o/gate)
constexpr size_t OFF_XM    = 0;          // [5][T][1024] f32 (kA -> kB)
constexpr size_t OFF_WFIN  = 0;          // [T][512] f32   (kC -> kD1)
constexpr size_t OFF_QE    = 8388608;    // [T][512] f32   (kD1 -> kD3)
constexpr size_t OFF_O     = 16777216;   // [T][1024] f32  (kD1/kD3 -> kE)
constexpr size_t OFF_GATE  = 33554432;   // [T][1024] f32  (kE -> kF)
constexpr size_t OFF_YCAT  = 83886080;   // [T][3136] f32
constexpr size_t OFF_WKV   = 135266304;  // [B*H*NCH][128][256] f32 (in-place scan)
constexpr size_t OFF_DECAY = 202375168;  // [B*H*NCH][128] f32
constexpr size_t WS_NEED   = 202637312;

DEVI float4 ld4(const float* p) { return *reinterpret_cast<const float4*>(p); }
DEVI void   st4(float* p, float4 v) { *reinterpret_cast<float4*>(p) = v; }

// ---------------------------------------------------------------- kernel A
// per 8 tokens: delta = x_prev - x; xm0 = x + delta*mu; t160 = tanh(xm0 @ x0_w.T)
// mix[n][h] = t160[n*32..] . x2_w[h][n*32..] + bias; xm_n = xm0 + delta*(mix - mu)
__global__ __launch_bounds__(256) void kA(
    const float* __restrict__ x, const float* __restrict__ x0_mu,
    const float* __restrict__ x0_w, const float* __restrict__ x2_w,
    const float* __restrict__ x_bias, float* __restrict__ xmG) {
  extern __shared__ float sm[];
  float* xm0  = sm;              // [8][1024]
  float* dsb  = xm0 + 8 * 1024;  // [8][1024]
  float* t160 = dsb + 8 * 1024;  // [8][160]
  float* wt   = t160 + 8 * 160;  // [256][33] padded weight tile
  const int tid = threadIdx.x;
  const int t0  = blockIdx.x * 8;

  for (int base = tid * 4; base < 8 * 1024; base += 1024) {
    int i = base >> 10, h = base & 1023;
    int t = t0 + i;
    float4 xv = ld4(x + (size_t)t * 1024 + h);
    float4 xp = make_float4(0.f, 0.f, 0.f, 0.f);
    if ((t & (Lc - 1)) != 0) xp = ld4(x + (size_t)(t - 1) * 1024 + h);
    float4 mu = ld4(x0_mu + h);
    float4 d; d.x = xp.x - xv.x; d.y = xp.y - xv.y; d.z = xp.z - xv.z; d.w = xp.w - xv.w;
    st4(dsb + base, d);
    float4 m0; m0.x = xv.x + d.x * mu.x; m0.y = xv.y + d.y * mu.y;
    m0.z = xv.z + d.z * mu.z; m0.w = xv.w + d.w * mu.w;
    st4(xm0 + base, m0);
  }
  __syncthreads();
  {  // t160: 8 tokens x 160 outputs, dot length 1024
    const int i2 = tid >> 5, rr = tid & 31;
    const float* a = xm0 + i2 * 1024;
    for (int rb = 0; rb < 5; ++rb) {
      const int r = rb * 32 + rr;
      const float* wrow = x0_w + (size_t)r * 1024;
      float a0 = 0, a1 = 0, a2 = 0, a3 = 0;
      for (int h = 0; h < 1024; h += 4) {
        float4 av = ld4(a + h);
        float4 wv = ld4(wrow + h);
        a0 += av.x * wv.x; a1 += av.y * wv.y; a2 += av.z * wv.z; a3 += av.w * wv.w;
      }
      t160[i2 * 160 + r] = tanhf((a0 + a1) + (a2 + a3));
    }
  }
  for (int n = 0; n < 5; ++n) {
    for (int ht = 0; ht < 4; ++ht) {
      const int h0 = ht * 256;
      __syncthreads();
      {  // load x2_w[:, n*32:(n+1)*32] tile for rows h0..h0+255
        const float* row = x2_w + (size_t)(h0 + tid) * 160 + n * 32;
        #pragma unroll
        for (int j = 0; j < 32; j += 4) {
          float4 w4 = ld4(row + j);
          wt[tid * 33 + j + 0] = w4.x; wt[tid * 33 + j + 1] = w4.y;
          wt[tid * 33 + j + 2] = w4.z; wt[tid * 33 + j + 3] = w4.w;
        }
      }
      __syncthreads();
      const int h = h0 + tid;
      const float mu0  = x0_mu[h];
      const float bias = x_bias[n * 1024 + h];
      const float* wp = wt + tid * 33;
      for (int i = 0; i < 8; ++i) {
        const float* tp = t160 + i * 160 + n * 32;
        float acc = bias;
        #pragma unroll
        for (int r = 0; r < 32; ++r) acc += tp[r] * wp[r];
        float outv = xm0[i * 1024 + h] + dsb[i * 1024 + h] * (acc - mu0);
        xmG[((size_t)n * Tc + (t0 + i)) * 1024 + h] = outv;
      }
    }
  }
}

// ------------------------------------------------- fp32 GEMM core 128x128x16
// C[128][ncols<=128] = A[128][1024] @ W[ncols][1024]^T, 8x8 per thread.
DEVI void gemm_core_128(const float* __restrict__ Ap, const float* __restrict__ Wp,
                        float* __restrict__ Cp, int ldc, int ncols,
                        float* __restrict__ As, float* __restrict__ Bs) {
  const int tid  = threadIdx.x;
  const int lrow = tid >> 2;         // 0..63
  const int lc4  = (tid & 3) * 4;    // 0,4,8,12
  const int tm   = tid >> 4;         // 0..15
  const int tn   = tid & 15;         // 0..15
  float acc[8][8];
  #pragma unroll
  for (int i = 0; i < 8; ++i)
    #pragma unroll
    for (int j = 0; j < 8; ++j) acc[i][j] = 0.f;

  const int wr0 = (lrow < ncols) ? lrow : 0;
  const int wr1 = (lrow + 64 < ncols) ? (lrow + 64) : 0;

  for (int k0 = 0; k0 < 1024; k0 += 16) {
    float4 a0 = ld4(Ap + (size_t)lrow * 1024 + k0 + lc4);
    float4 a1 = ld4(Ap + (size_t)(lrow + 64) * 1024 + k0 + lc4);
    float4 b0 = ld4(Wp + (size_t)wr0 * 1024 + k0 + lc4);
    float4 b1 = ld4(Wp + (size_t)wr1 * 1024 + k0 + lc4);
    __syncthreads();
    As[(lc4 + 0) * 132 + lrow] = a0.x; As[(lc4 + 1) * 132 + lrow] = a0.y;
    As[(lc4 + 2) * 132 + lrow] = a0.z; As[(lc4 + 3) * 132 + lrow] = a0.w;
    As[(lc4 + 0) * 132 + lrow + 64] = a1.x; As[(lc4 + 1) * 132 + lrow + 64] = a1.y;
    As[(lc4 + 2) * 132 + lrow + 64] = a1.z; As[(lc4 + 3) * 132 + lrow + 64] = a1.w;
    Bs[(lc4 + 0) * 132 + lrow] = b0.x; Bs[(lc4 + 1) * 132 + lrow] = b0.y;
    Bs[(lc4 + 2) * 132 + lrow] = b0.z; Bs[(lc4 + 3) * 132 + lrow] = b0.w;
    Bs[(lc4 + 0) * 132 + lrow + 64] = b1.x; Bs[(lc4 + 1) * 132 + lrow + 64] = b1.y;
    Bs[(lc4 + 2) * 132 + lrow + 64] = b1.z; Bs[(lc4 + 3) * 132 + lrow + 64] = b1.w;
    __syncthreads();
    #pragma unroll
    for (int kk = 0; kk < 16; ++kk) {
      float4 af0 = ld4(As + kk * 132 + tm * 4);
      float4 af1 = ld4(As + kk * 132 + 64 + tm * 4);
      float4 bf0 = ld4(Bs + kk * 132 + tn * 4);
      float4 bf1 = ld4(Bs + kk * 132 + 64 + tn * 4);
      float av[8] = {af0.x, af0.y, af0.z, af0.w, af1.x, af1.y, af1.z, af1.w};
      float bv[8] = {bf0.x, bf0.y, bf0.z, bf0.w, bf1.x, bf1.y, bf1.z, bf1.w};
      #pragma unroll
      for (int i = 0; i < 8; ++i)
        #pragma unroll
        for (int j = 0; j < 8; ++j) acc[i][j] += av[i] * bv[j];
    }
  }
  #pragma unroll
  for (int i = 0; i < 8; ++i) {
    int row = (i < 4) ? (tm * 4 + i) : (64 + tm * 4 + (i - 4));
    #pragma unroll
    for (int jh = 0; jh < 2; ++jh) {
      int col = jh * 64 + tn * 4;
      if (col < ncols) {
        float4 v;
        v.x = acc[i][jh * 4 + 0]; v.y = acc[i][jh * 4 + 1];
        v.z = acc[i][jh * 4 + 2]; v.w = acc[i][jh * 4 + 3];
        st4(Cp + (size_t)row * ldc + col, v);
      }
    }
  }
}

// --------------------------------------------------------------- kernel B
// ycat[T][3136] = [r | wpre | k | v | g]; segment picks its mixed A-plane.
__global__ __launch_bounds__(256) void kB(
    const float* __restrict__ xmG, const float* __restrict__ r_w,
    const float* __restrict__ w_w1, const float* __restrict__ k_w,
    const float* __restrict__ v_w, const float* __restrict__ g_w,
    float* __restrict__ ycat) {
  __shared__ float As[16 * 132];
  __shared__ float Bs[16 * 132];
  const int mt = blockIdx.x, nt = blockIdx.y;
  int seg, col0, ncols = 128;
  const float* W;
  if (nt < 4)       { seg = 0; W = r_w + (size_t)nt * 128 * 1024;        col0 = nt * 128; }
  else if (nt == 4) { seg = 1; W = w_w1;                                 col0 = 512; ncols = 64; }
  else if (nt < 9)  { seg = 2; W = k_w + (size_t)(nt - 5) * 128 * 1024;  col0 = 576 + (nt - 5) * 128; }
  else if (nt < 17) { seg = 3; W = v_w + (size_t)(nt - 9) * 128 * 1024;  col0 = 1088 + (nt - 9) * 128; }
  else              { seg = 4; W = g_w + (size_t)(nt - 17) * 128 * 1024; col0 = 2112 + (nt - 17) * 128; }
  const float* Ap = xmG + ((size_t)seg * Tc + (size_t)mt * 128) * 1024;
  float* Cp = ycat + (size_t)mt * 128 * 3136 + col0;
  gemm_core_128(Ap, W, Cp, 3136, ncols, As, Bs);
}

// --------------------------------------------------------------- kernel C
// wfin[t][c] = -exp( tanh(ycat[t][512..576]) . w_w2[c] + w_b2[c] )
__global__ __launch_bounds__(256) void kC(
    const float* __restrict__ ycat, const float* __restrict__ w_w2,
    const float* __restrict__ w_b2, float* __restrict__ wfin) {
  __shared__ float th[32 * 64];
  const int tid = threadIdx.x;
  const int t0  = blockIdx.x * 32;
  for (int idx = tid; idx < 32 * 64; idx += 256) {
    int i = idx >> 6, j = idx & 63;
    th[idx] = tanhf(ycat[(size_t)(t0 + i) * 3136 + 512 + j]);
  }
  __syncthreads();
  const int c = blockIdx.y * 256 + tid;
  float acc[32];
  #pragma unroll
  for (int i = 0; i < 32; ++i) acc[i] = 0.f;
  const float* w2 = w_w2 + (size_t)c * 64;
  for (int k = 0; k < 64; k += 4) {
    float4 wv = ld4(w2 + k);
    #pragma unroll
    for (int i = 0; i < 32; ++i) {
      acc[i] += th[i * 64 + k] * wv.x + th[i * 64 + k + 1] * wv.y +
                th[i * 64 + k + 2] * wv.z + th[i * 64 + k + 3] * wv.w;
    }
  }
  const float b = w_b2[c];
  #pragma unroll
  for (int i = 0; i < 32; ++i)
    wfin[(size_t)(t0 + i) * 512 + c] = -__expf(acc[i] + b);
}

// --------------------------------------------------------------- kernel D1
// per (b,h,chunk): cumsum w; qe,ke,kw,decay; wkv = kw^T v; A (strict-lower,
// diag = q.u.k on the diagonal); o_intra = A @ v. Writes wkv, decay, qe, o.
__global__ __launch_bounds__(256) void kD1(
    const float* __restrict__ ycat, const float* __restrict__ wfin,
    const float* __restrict__ bonus, float* __restrict__ wkvG,
    float* __restrict__ decayG, float* __restrict__ qeG, float* __restrict__ oG) {
  extern __shared__ float sm[];
  float* wcl  = sm;                 // [32][129] w then cumsum
  float* kwl  = wcl + 32 * 129;     // [32][129]
  float* qeT  = kwl + 32 * 129;     // [128][36] transposed for A
  float* keT  = qeT + 128 * 36;     // [128][36]
  float* vl   = keT + 128 * 36;     // [32][256]
  float* Al   = vl + 32 * 256;      // [32][32]
  float* diag = Al + 1024;          // [32]
  const int tid = threadIdx.x;
  const int bid = blockIdx.x;       // (b*H + h)*64 + nc
  const int nc = bid & 63, h = (bid >> 6) & 3, b = bid >> 8;
  const int tb = b * Lc + nc * 32;

  for (int it = 0; it < 16; ++it) {
    int idx = it * 256 + tid;
    int c = idx >> 7, d = idx & 127;
    wcl[c * 129 + d] = wfin[(size_t)(tb + c) * 512 + h * 128 + d];
  }
  for (int base = tid * 4; base < 32 * 256; base += 1024) {
    int c = base >> 8, p = base & 255;
    st4(vl + c * 256 + p, ld4(ycat + (size_t)(tb + c) * 3136 + 1088 + h * 256 + p));
  }
  __syncthreads();
  if (tid < 128) {  // inclusive cumsum along chunk dim
    const int d = tid;
    float wv_[32];
    #pragma unroll
    for (int c = 0; c < 32; ++c) wv_[c] = wcl[c * 129 + d];
    float run = 0.f;
    #pragma unroll
    for (int c = 0; c < 32; ++c) { run += wv_[c]; wcl[c * 129 + d] = run; }
  } else if (tid < 160) {  // diag[i] = sum_d q*u*k
    const int i = tid - 128;
    const float* qrow = ycat + (size_t)(tb + i) * 3136 + h * 128;
    const float* krow = ycat + (size_t)(tb + i) * 3136 + 576 + h * 128;
    const float* u = bonus + h * 128;
    float s0 = 0, s1 = 0, s2 = 0, s3 = 0;
    for (int d = 0; d < 128; d += 4) {
      s0 += qrow[d + 0] * u[d + 0] * krow[d + 0];
      s1 += qrow[d + 1] * u[d + 1] * krow[d + 1];
      s2 += qrow[d + 2] * u[d + 2] * krow[d + 2];
      s3 += qrow[d + 3] * u[d + 3] * krow[d + 3];
    }
    diag[i] = (s0 + s1) + (s2 + s3);
  }
  __syncthreads();
  for (int it = 0; it < 16; ++it) {  // qe/ke/kw/decay elementwise
    int idx = it * 256 + tid;
    int c = idx >> 7, d = idx & 127;
    int t = tb + c;
    float q = ycat[(size_t)t * 3136 + h * 128 + d];
    float k = ycat[(size_t)t * 3136 + 576 + h * 128 + d];
    float wcc = wcl[c * 129 + d];
    float wcp = (c > 0) ? wcl[(c - 1) * 129 + d] : 0.f;
    float wlast = wcl[31 * 129 + d];
    float qe = q * __expf(wcp);
    float ke = k * __expf(-wcc);
    float kv = k * __expf(wlast - wcc);
    qeT[d * 36 + c] = qe;
    keT[d * 36 + c] = ke;
    kwl[c * 129 + d] = kv;
    qeG[(size_t)t * 512 + h * 128 + d] = qe;
    if (c == 31) decayG[(size_t)bid * 128 + d] = __expf(wlast);
  }
  __syncthreads();
  const int pid = tid & 63, wvx = tid >> 6;
  const int p4 = pid * 4;
  {  // wkv[d][p] = sum_c kw[c][d] * v[c][p]
    float* wkvB = wkvG + (size_t)bid * (128 * 256);
    for (int pp = 0; pp < 4; ++pp) {
      const int d0 = pp * 32 + wvx * 8;
      float4 acc[8];
      #pragma unroll
      for (int q = 0; q < 8; ++q) acc[q] = make_float4(0, 0, 0, 0);
      for (int c = 0; c < 32; ++c) {
        float4 v4 = ld4(vl + c * 256 + p4);
        #pragma unroll
        for (int q = 0; q < 8; ++q) {
          float s = kwl[c * 129 + d0 + q];
          acc[q].x += v4.x * s; acc[q].y += v4.y * s;
          acc[q].z += v4.z * s; acc[q].w += v4.w * s;
        }
      }
      #pragma unroll
      for (int q = 0; q < 8; ++q) st4(wkvB + (size_t)(d0 + q) * 256 + p4, acc[q]);
    }
  }
  {  // A[i][j]
    const int i4 = tid >> 3;
    const int j4 = (tid & 7) * 4;
    float4 accA = make_float4(0, 0, 0, 0);
    for (int d = 0; d < 128; ++d) {
      float qv = qeT[d * 36 + i4];
      float4 kv = ld4(keT + d * 36 + j4);
      accA.x += kv.x * qv; accA.y += kv.y * qv;
      accA.z += kv.z * qv; accA.w += kv.w * qv;
    }
    float av[4] = {accA.x, accA.y, accA.z, accA.w};
    #pragma unroll
    for (int jj = 0; jj < 4; ++jj) {
      int j = j4 + jj;
      Al[i4 * 32 + j] = (j < i4) ? av[jj] : ((j == i4) ? diag[i4] : 0.f);
    }
  }
  __syncthreads();
  {  // o_intra = A @ v  (diag folded into A)
    float4 acc[8];
    #pragma unroll
    for (int q = 0; q < 8; ++q) acc[q] = make_float4(0, 0, 0, 0);
    for (int c = 0; c < 32; ++c) {
      float4 v4 = ld4(vl + c * 256 + p4);
      #pragma unroll
      for (int q = 0; q < 8; ++q) {
        float a = Al[(wvx * 8 + q) * 32 + c];
        acc[q].x += v4.x * a; acc[q].y += v4.y * a;
        acc[q].z += v4.z * a; acc[q].w += v4.w * a;
      }
    }
    #pragma unroll
    for (int q = 0; q < 8; ++q)
      st4(oG + (size_t)(tb + wvx * 8 + q) * 1024 + h * 256 + p4, acc[q]);
  }
}

// --------------------------------------------------------------- kernel D2
// inter-chunk scan per (b,h,d)-row; in-place: wkv[nc] is replaced by the state
// BEFORE chunk nc. One wave per row; lane holds 4 columns.
__global__ __launch_bounds__(256) void kD2(float* __restrict__ wkvG,
                                           const float* __restrict__ decayG) {
  const int wvid = (blockIdx.x * 256 + threadIdx.x) >> 6;  // 0..1023
  const int lane = threadIdx.x & 63;
  const int p4 = lane * 4;
  const int d = wvid & 127;
  const int bh = wvid >> 7;  // b*H + h
  float* base = wkvG + ((size_t)bh * 64 * 128 + d) * 256 + p4;
  const float* dbase = decayG + (size_t)bh * 64 * 128 + d;
  float4 S = make_float4(0, 0, 0, 0);
  float4 kv_n = ld4(base);
  float dec_n = dbase[0];
  for (int nc = 0; nc < 64; ++nc) {
    float4 kv = kv_n;
    float dec = dec_n;
    if (nc < 63) {
      kv_n = ld4(base + (size_t)(nc + 1) * 32768);
      dec_n = dbase[(size_t)(nc + 1) * 128];
    }
    st4(base + (size_t)nc * 32768, S);
    S.x = S.x * dec + kv.x; S.y = S.y * dec + kv.y;
    S.z = S.z * dec + kv.z; S.w = S.w * dec + kv.w;
  }
}

// --------------------------------------------------------------- kernel D3
// o += qe @ S_before  per chunk
__global__ __launch_bounds__(256) void kD3(
    const float* __restrict__ qeG, const float* __restrict__ wkvG,
    float* __restrict__ oG) {
  __shared__ float qel[32 * 129];
  const int tid = threadIdx.x;
  const int bid = blockIdx.x;
  const int nc = bid & 63, h = (bid >> 6) & 3, b = bid >> 8;
  const int tb = b * Lc + nc * 32;
  for (int it = 0; it < 16; ++it) {
    int idx = it * 256 + tid;
    int c = idx >> 7, d = idx & 127;
    qel[c * 129 + d] = qeG[(size_t)(tb + c) * 512 + h * 128 + d];
  }
  __syncthreads();
  const int pid = tid & 63, wvx = tid >> 6;
  const int p4 = pid * 4;
  const float* Sb = wkvG + (size_t)bid * (128 * 256);
  float4 acc[8];
  #pragma unroll
  for (int q = 0; q < 8; ++q) acc[q] = make_float4(0, 0, 0, 0);
  for (int d = 0; d < 128; ++d) {
    float4 s4 = ld4(Sb + (size_t)d * 256 + p4);
    #pragma unroll
    for (int q = 0; q < 8; ++q) {
      float qv = qel[(wvx * 8 + q) * 129 + d];
      acc[q].x += s4.x * qv; acc[q].y += s4.y * qv;
      acc[q].z += s4.z * qv; acc[q].w += s4.w * qv;
    }
  }
  #pragma unroll
  for (int q = 0; q < 8; ++q) {
    float* op = oG + (size_t)(tb + wvx * 8 + q) * 1024 + h * 256 + p4;
    float4 cur = ld4(op);
    cur.x += acc[q].x; cur.y += acc[q].y; cur.z += acc[q].z; cur.w += acc[q].w;
    st4(op, cur);
  }
}

// --------------------------------------------------------------- kernel E
// GroupNorm (per head, 256 ch) + swish gate; gate = on * g*sigmoid(g)
__global__ __launch_bounds__(256) void kE(
    const float* __restrict__ oG, const float* __restrict__ ycat,
    const float* __restrict__ gn_w, const float* __restrict__ gn_b,
    float* __restrict__ gate) {
  const int t = blockIdx.x;
  const int h = threadIdx.x >> 6, lane = threadIdx.x & 63;
  const int p4 = lane * 4;
  const int vd = h * 256 + p4;
  float4 v = ld4(oG + (size_t)t * 1024 + vd);
  float s = v.x + v.y + v.z + v.w;
  float ss = v.x * v.x + v.y * v.y + v.z * v.z + v.w * v.w;
  for (int m = 1; m < 64; m <<= 1) {
    s += __shfl_xor(s, m, 64);
    ss += __shfl_xor(ss, m, 64);
  }
  const float mean = s * (1.f / 256.f);
  const float var = ss * (1.f / 256.f) - mean * mean;
  const float rs = rsqrtf(var + 1e-5f);
  float4 gw = ld4(gn_w + vd), gb = ld4(gn_b + vd);
  float4 on;
  on.x = (v.x - mean) * rs * gw.x + gb.x;
  on.y = (v.y - mean) * rs * gw.y + gb.y;
  on.z = (v.z - mean) * rs * gw.z + gb.z;
  on.w = (v.w - mean) * rs * gw.w + gb.w;
  float4 g4 = ld4(ycat + (size_t)t * 3136 + 2112 + vd);
  float4 sw;
  sw.x = g4.x / (1.f + __expf(-g4.x));
  sw.y = g4.y / (1.f + __expf(-g4.y));
  sw.z = g4.z / (1.f + __expf(-g4.z));
  sw.w = g4.w / (1.f + __expf(-g4.w));
  float4 outv;
  outv.x = on.x * sw.x; outv.y = on.y * sw.y;
  outv.z = on.z * sw.z; outv.w = on.w * sw.w;
  st4(gate + (size_t)t * 1024 + vd, outv);
}

// --------------------------------------------------------------- kernel F
__global__ __launch_bounds__(256) void kF(
    const float* __restrict__ gate, const float* __restrict__ o_w,
    float* __restrict__ out) {
  __shared__ float As[16 * 132];
  __shared__ float Bs[16 * 132];
  const int mt = blockIdx.x, nt = blockIdx.y;
  gemm_core_128(gate + (size_t)mt * 128 * 1024,
                o_w + (size_t)nt * 128 * 1024,
                out + (size_t)mt * 128 * 1024 + nt * 128, 1024, 128, As, Bs);
}

}  // namespace

extern "C" void kernel_launch(void* const* d_in, const int* in_sizes, int n_in,
                              void* d_out, int out_size, void* d_ws, size_t ws_size,
                              hipStream_t stream) {
  (void)in_sizes; (void)n_in; (void)out_size;
  if (ws_size < WS_NEED) return;  // needs ~203 MB scratch

  const float* x      = (const float*)d_in[0];
  const float* x0_mu  = (const float*)d_in[1];
  const float* x0_w   = (const float*)d_in[2];
  const float* x2_w   = (const float*)d_in[3];
  const float* x_bias = (const float*)d_in[4];
  const float* r_w    = (const float*)d_in[5];
  const float* w_w1   = (const float*)d_in[6];
  const float* w_w2   = (const float*)d_in[7];
  const float* w_b2   = (const float*)d_in[8];
  const float* k_w    = (const float*)d_in[9];
  const float* v_w    = (const float*)d_in[10];
  const float* g_w    = (const float*)d_in[11];
  const float* bonus  = (const float*)d_in[12];
  const float* gn_w   = (const float*)d_in[13];
  const float* gn_b   = (const float*)d_in[14];
  const float* o_w    = (const float*)d_in[15];
  float* out = (float*)d_out;
  char* ws = (char*)d_ws;

  float* xmG    = (float*)(ws + OFF_XM);
  float* wfin   = (float*)(ws + OFF_WFIN);
  float* qeG    = (float*)(ws + OFF_QE);
  float* oG     = (float*)(ws + OFF_O);
  float* gate   = (float*)(ws + OFF_GATE);
  float* ycat   = (float*)(ws + OFF_YCAT);
  float* wkvG   = (float*)(ws + OFF_WKV);
  float* decayG = (float*)(ws + OFF_DECAY);

  const size_t ldsA  = (size_t)(8 * 1024 * 2 + 8 * 160 + 256 * 33) * 4;       // 104448 B
  const size_t ldsD1 = (size_t)(32 * 129 * 2 + 128 * 36 * 2 + 32 * 256 + 1024 + 32) * 4;  // 106880 B

  kA<<<dim3(Tc / 8), dim3(256), ldsA, stream>>>(x, x0_mu, x0_w, x2_w, x_bias, xmG);
  kB<<<dim3(32, 25), dim3(256), 0, stream>>>(xmG, r_w, w_w1, k_w, v_w, g_w, ycat);
  kC<<<dim3(128, 2), dim3(256), 0, stream>>>(ycat, w_w2, w_b2, wfin);
  kD1<<<dim3(Bc * NHc * NCHc), dim3(256), ldsD1, stream>>>(ycat, wfin, bonus, wkvG,
                                                           decayG, qeG, oG);
  kD2<<<dim3(256), dim3(256), 0, stream>>>(wkvG, decayG);
  kD3<<<dim3(Bc * NHc * NCHc), dim3(256), 0, stream>>>(qeG, wkvG, oG);
  kE<<<dim3(Tc), dim3(256), 0, stream>>>(oG, ycat, gn_w, gn_b, gate);
  kF<<<dim3(32, 8), dim3(256), 0, stream>>>(gate, o_w, out);
}

// Round 4
// 548.247 us; speedup vs baseline: 2.3656x; 2.3656x over previous
//
#include <hip/hip_runtime.h>

// RWKV6Attention forward — round 4: bf16x3 (split hi/lo) MFMA projections,
// fully-f32 numerics everywhere sensitive. Only g-projection, gate, and the
// output GEMM use single-pass bf16 (insensitive paths).

#define DEVI __device__ __forceinline__

namespace {

typedef unsigned short u16;
typedef unsigned int u32;
typedef __attribute__((ext_vector_type(8))) short short8;   // 8 bf16 (4 VGPRs)
typedef __attribute__((ext_vector_type(4))) float f32x4;

typedef __attribute__((address_space(1))) const u32 gu32;
typedef __attribute__((address_space(3))) u32 lu32;

constexpr int Lc = 2048;
constexpr int Tc = 4096;   // B*L

// ---- workspace layout (byte offsets), lifetime-safe aliasing.
// wkv region [0, 67.1M): tenants all dead before kD1 writes wkv.
constexpr size_t OFF_WKV   = 0;            // f32 [512][128][256]
constexpr size_t OFF_XM0   = 0;            // f32 [T][1024]   dead after kA2mf
constexpr size_t OFF_DELTA = 16777216;     // f32 [T][1024]   dead after kA2mf
constexpr size_t OFF_T160  = 33554432;     // f32 [T][160]    dead after kA2mf
constexpr size_t OFF_XMW   = 36175872;     // f32 [T][1024]   dead after kWL
constexpr size_t OFF_WSP   = 52953088;     // bf16 Whi[3072][1024] + Wlo, dead after kB
constexpr size_t OFF_YW    = 65536000;     // f32 [T][64]     dead after kC (kC < kD1)
// xmf region [67.1M, 134.2M): dead after kB; re-tenanted by kD1/kE outputs.
constexpr size_t OFF_XMF   = 67108864;     // f32 [4][T][1024]
constexpr size_t OFF_OO    = 67108864;     // f32 [T][1024]   kD1 w
constexpr size_t OFF_QE    = 83886080;     // f32 [T][512]    kD1 w
constexpr size_t OFF_DECAY = 92274688;     // f32 [512][128]  kD1 w
constexpr size_t OFF_GATE  = 92536832;     // bf16 [T][1024]  kE w
// persistent
constexpr size_t OFF_RG    = 134217728;    // f32 [T][512]
constexpr size_t OFF_KG    = 142606336;    // f32 [T][512]
constexpr size_t OFF_VG    = 150994944;    // f32 [T][1024]
constexpr size_t OFF_GG    = 167772160;    // bf16 [T][1024]
constexpr size_t OFF_WFIN  = 176160768;    // f32 [T][512]
constexpr size_t OFF_OWB   = 184549376;    // bf16 [1024][1024]
constexpr size_t WS_NEED   = 186646528;

constexpr size_t WLO_OFF_E = 3145728;      // Wlo element offset inside WSP

DEVI float4 ld4(const float* p) { return *reinterpret_cast<const float4*>(p); }
DEVI void   st4(float* p, float4 v) { *reinterpret_cast<float4*>(p) = v; }
DEVI u16 f2bf(float f) {
  u32 u = __float_as_uint(f);
  return (u16)((u + 0x7FFFu + ((u >> 16) & 1u)) >> 16);
}
DEVI float bf2f(u16 u) { return __uint_as_float((u32)u << 16); }

// ---------------------------------------------------------------- kernel W
// split r|k|v|g weights -> Whi/Wlo bf16; o_w -> owb bf16 single.
__global__ void kW(const float* __restrict__ r_w, const float* __restrict__ k_w,
                   const float* __restrict__ v_w, const float* __restrict__ g_w,
                   const float* __restrict__ o_w, u16* __restrict__ Whi,
                   u16* __restrict__ Wlo, u16* __restrict__ owb) {
  const size_t i = ((size_t)blockIdx.x * 256 + threadIdx.x) * 4;
  const float* src;
  u16 *dhi, *dlo = nullptr;
  if (i < 524288)       { src = r_w + i;             dhi = Whi + i; dlo = Wlo + i; }
  else if (i < 1048576) { src = k_w + (i - 524288);  dhi = Whi + i; dlo = Wlo + i; }
  else if (i < 2097152) { src = v_w + (i - 1048576); dhi = Whi + i; dlo = Wlo + i; }
  else if (i < 3145728) { src = g_w + (i - 2097152); dhi = Whi + i; dlo = Wlo + i; }
  else                  { src = o_w + (i - 3145728); dhi = owb + (i - 3145728); }
  float4 v = ld4(src);
  ushort4 h;
  h.x = f2bf(v.x); h.y = f2bf(v.y); h.z = f2bf(v.z); h.w = f2bf(v.w);
  *reinterpret_cast<ushort4*>(dhi) = h;
  if (dlo) {
    ushort4 l;
    l.x = f2bf(v.x - bf2f(h.x)); l.y = f2bf(v.y - bf2f(h.y));
    l.z = f2bf(v.z - bf2f(h.z)); l.w = f2bf(v.w - bf2f(h.w));
    *reinterpret_cast<ushort4*>(dlo) = l;
  }
}

// ---------------------------------------------------------------- kernel A1
__global__ void kA1(const float* __restrict__ x, const float* __restrict__ x0_mu,
                    float* __restrict__ xm0, float* __restrict__ delta) {
  const size_t i4 = (size_t)blockIdx.x * 256 + threadIdx.x;
  const int t = (int)(i4 >> 8);
  const int h4 = (int)(i4 & 255) * 4;
  float4 xv = ld4(x + (size_t)t * 1024 + h4);
  float4 xp = make_float4(0.f, 0.f, 0.f, 0.f);
  if (t & (Lc - 1)) xp = ld4(x + (size_t)(t - 1) * 1024 + h4);
  float4 mu = ld4(x0_mu + h4);
  float4 d;
  d.x = xp.x - xv.x; d.y = xp.y - xv.y; d.z = xp.z - xv.z; d.w = xp.w - xv.w;
  st4(delta + (size_t)t * 1024 + h4, d);
  float4 m0;
  m0.x = xv.x + d.x * mu.x; m0.y = xv.y + d.y * mu.y;
  m0.z = xv.z + d.z * mu.z; m0.w = xv.w + d.w * mu.w;
  st4(xm0 + (size_t)t * 1024 + h4, m0);
}

// ---------------------------------------------------------------- kernel A2
// t160[T][160] = tanh(xm0 @ x0_w^T), fp32
__global__ __launch_bounds__(256) void kA2(
    const float* __restrict__ xm0, const float* __restrict__ x0_w,
    float* __restrict__ t160) {
  __shared__ float As[128 * 33];
  __shared__ float Ws[32 * 33];
  const int tid = threadIdx.x;
  const int m0 = blockIdx.x * 128;
  const int n0 = blockIdx.y * 32;
  const int trow = (tid >> 3) * 4;
  const int tn4 = (tid & 7) * 4;
  float acc[4][4] = {};
  for (int k0 = 0; k0 < 1024; k0 += 32) {
    __syncthreads();
    #pragma unroll
    for (int c = 0; c < 4; ++c) {
      int r = c * 32 + (tid >> 3);
      int col = (tid & 7) * 4;
      float4 a4 = ld4(xm0 + (size_t)(m0 + r) * 1024 + k0 + col);
      As[r * 33 + col + 0] = a4.x; As[r * 33 + col + 1] = a4.y;
      As[r * 33 + col + 2] = a4.z; As[r * 33 + col + 3] = a4.w;
    }
    {
      int r = tid >> 3;
      int col = (tid & 7) * 4;
      float4 w4 = ld4(x0_w + (size_t)(n0 + r) * 1024 + k0 + col);
      Ws[r * 33 + col + 0] = w4.x; Ws[r * 33 + col + 1] = w4.y;
      Ws[r * 33 + col + 2] = w4.z; Ws[r * 33 + col + 3] = w4.w;
    }
    __syncthreads();
    #pragma unroll
    for (int kk = 0; kk < 32; ++kk) {
      float a[4], w[4];
      #pragma unroll
      for (int i = 0; i < 4; ++i) a[i] = As[(trow + i) * 33 + kk];
      #pragma unroll
      for (int j = 0; j < 4; ++j) w[j] = Ws[(tn4 + j) * 33 + kk];
      #pragma unroll
      for (int i = 0; i < 4; ++i)
        #pragma unroll
        for (int j = 0; j < 4; ++j) acc[i][j] += a[i] * w[j];
    }
  }
  #pragma unroll
  for (int i = 0; i < 4; ++i)
    #pragma unroll
    for (int j = 0; j < 4; ++j)
      t160[(size_t)(m0 + trow + i) * 160 + n0 + tn4 + j] = tanhf(acc[i][j]);
}

// ---------------------------------------------------------------- kernel A2mf
// fused: per 64x64 (t,h) tile, for each n: mix = t160slice @ x2_wslice^T + bias;
// plane_n = xm0 + delta*(mix - mu). n==1 -> f32 xmw; else f32 xmf plane.
__global__ __launch_bounds__(256) void kA2mf(
    const float* __restrict__ t160G, const float* __restrict__ x2_w,
    const float* __restrict__ x_bias, const float* __restrict__ xm0,
    const float* __restrict__ delta, const float* __restrict__ x0_mu,
    float* __restrict__ xmf, float* __restrict__ xmw) {
  __shared__ float As[64 * 33];
  __shared__ float Ws[64 * 33];
  const int tid = threadIdx.x;
  const int m0 = blockIdx.x * 64, h0 = blockIdx.y * 64;
  const int rm = (tid >> 4) * 4, cn = (tid & 15) * 4;
  float4 xm4[4], dv4[4];
  #pragma unroll
  for (int i = 0; i < 4; ++i) {
    xm4[i] = ld4(xm0 + (size_t)(m0 + rm + i) * 1024 + h0 + cn);
    dv4[i] = ld4(delta + (size_t)(m0 + rm + i) * 1024 + h0 + cn);
  }
  const float4 mu4 = ld4(x0_mu + h0 + cn);
  for (int n = 0; n < 5; ++n) {
    __syncthreads();
    #pragma unroll
    for (int c = 0; c < 2; ++c) {
      int r = c * 32 + (tid >> 3);
      int col = (tid & 7) * 4;
      float4 a4 = ld4(t160G + (size_t)(m0 + r) * 160 + n * 32 + col);
      As[r * 33 + col + 0] = a4.x; As[r * 33 + col + 1] = a4.y;
      As[r * 33 + col + 2] = a4.z; As[r * 33 + col + 3] = a4.w;
      float4 w4 = ld4(x2_w + (size_t)(h0 + r) * 160 + n * 32 + col);
      Ws[r * 33 + col + 0] = w4.x; Ws[r * 33 + col + 1] = w4.y;
      Ws[r * 33 + col + 2] = w4.z; Ws[r * 33 + col + 3] = w4.w;
    }
    __syncthreads();
    float acc[4][4] = {};
    #pragma unroll
    for (int kk = 0; kk < 32; ++kk) {
      float a[4], w[4];
      #pragma unroll
      for (int i = 0; i < 4; ++i) a[i] = As[(rm + i) * 33 + kk];
      #pragma unroll
      for (int j = 0; j < 4; ++j) w[j] = Ws[(cn + j) * 33 + kk];
      #pragma unroll
      for (int i = 0; i < 4; ++i)
        #pragma unroll
        for (int j = 0; j < 4; ++j) acc[i][j] += a[i] * w[j];
    }
    const float4 b4 = ld4(x_bias + n * 1024 + h0 + cn);
    #pragma unroll
    for (int i = 0; i < 4; ++i) {
      float4 o;
      o.x = xm4[i].x + dv4[i].x * (acc[i][0] + b4.x - mu4.x);
      o.y = xm4[i].y + dv4[i].y * (acc[i][1] + b4.y - mu4.y);
      o.z = xm4[i].z + dv4[i].z * (acc[i][2] + b4.z - mu4.z);
      o.w = xm4[i].w + dv4[i].w * (acc[i][3] + b4.w - mu4.w);
      if (n == 1) {
        st4(xmw + (size_t)(m0 + rm + i) * 1024 + h0 + cn, o);
      } else {
        int pi = (n == 0) ? 0 : n - 1;
        st4(xmf + ((size_t)pi * Tc + m0 + rm + i) * 1024 + h0 + cn, o);
      }
    }
  }
}

// ---------------------------------------------------------------- kernel WL
// y_w[T][64] = tanh(xmw @ w_w1^T), fp32
__global__ __launch_bounds__(256) void kWL(
    const float* __restrict__ xmw, const float* __restrict__ w_w1,
    float* __restrict__ yw) {
  __shared__ float As[32 * 33];
  __shared__ float Ws[64 * 33];
  const int tid = threadIdx.x;
  const int t0 = blockIdx.x * 32;
  const int rg = tid >> 5;
  const int cg = tid & 31;
  float acc[4][2] = {};
  for (int k0 = 0; k0 < 1024; k0 += 32) {
    __syncthreads();
    {
      int r = tid >> 3, c4 = (tid & 7) * 4;
      float4 a4 = ld4(xmw + (size_t)(t0 + r) * 1024 + k0 + c4);
      As[r * 33 + c4 + 0] = a4.x; As[r * 33 + c4 + 1] = a4.y;
      As[r * 33 + c4 + 2] = a4.z; As[r * 33 + c4 + 3] = a4.w;
    }
    #pragma unroll
    for (int c = 0; c < 2; ++c) {
      int r = c * 32 + (tid >> 3), c4 = (tid & 7) * 4;
      float4 w4 = ld4(w_w1 + (size_t)r * 1024 + k0 + c4);
      Ws[r * 33 + c4 + 0] = w4.x; Ws[r * 33 + c4 + 1] = w4.y;
      Ws[r * 33 + c4 + 2] = w4.z; Ws[r * 33 + c4 + 3] = w4.w;
    }
    __syncthreads();
    #pragma unroll
    for (int kk = 0; kk < 32; ++kk) {
      float a[4];
      #pragma unroll
      for (int i = 0; i < 4; ++i) a[i] = As[(rg * 4 + i) * 33 + kk];
      float w0 = Ws[cg * 33 + kk], w1 = Ws[(cg + 32) * 33 + kk];
      #pragma unroll
      for (int i = 0; i < 4; ++i) { acc[i][0] += a[i] * w0; acc[i][1] += a[i] * w1; }
    }
  }
  #pragma unroll
  for (int i = 0; i < 4; ++i) {
    yw[(size_t)(t0 + rg * 4 + i) * 64 + cg]      = tanhf(acc[i][0]);
    yw[(size_t)(t0 + rg * 4 + i) * 64 + cg + 32] = tanhf(acc[i][1]);
  }
}

// -------------------------------------------- bf16x3 MFMA GEMM core 128x128
// C = A(f32) @ W^T where W given split (Whi + Wlo). three=false -> hi*hi only.
__global__ __launch_bounds__(256) void kB(
    const float* __restrict__ xmf, const u16* __restrict__ Wsp,
    float* __restrict__ rG, float* __restrict__ kG,
    float* __restrict__ vG, u16* __restrict__ gG) {
  __shared__ __align__(16) u16 Ahi[128 * 64];
  __shared__ __align__(16) u16 Alo[128 * 64];
  __shared__ __align__(16) u16 Bhi[128 * 64];
  __shared__ __align__(16) u16 Blo[128 * 64];
  const int mt = blockIdx.x, nt = blockIdx.y;
  int plane, col0, ldc;
  float* Cf = nullptr;
  u16* Cb = nullptr;
  bool three = true;
  if (nt < 4)       { plane = 0; Cf = rG; ldc = 512;  col0 = nt * 128; }
  else if (nt < 8)  { plane = 1; Cf = kG; ldc = 512;  col0 = (nt - 4) * 128; }
  else if (nt < 16) { plane = 2; Cf = vG; ldc = 1024; col0 = (nt - 8) * 128; }
  else              { plane = 3; Cb = gG; ldc = 1024; col0 = (nt - 16) * 128; three = false; }
  const float* A  = xmf + ((size_t)plane * Tc + (size_t)mt * 128) * 1024;
  const u16* Whi = Wsp + (size_t)nt * 128 * 1024;
  const u16* Wlo = Whi + WLO_OFF_E;

  const int tid = threadIdx.x;
  const int lane = tid & 63;
  const int wv = tid >> 6;
  const int wr = wv >> 1, wc = wv & 1;
  const int srow = wv * 32;
  f32x4 acc[4][4];
  #pragma unroll
  for (int i = 0; i < 4; ++i)
    #pragma unroll
    for (int j = 0; j < 4; ++j) acc[i][j] = {0.f, 0.f, 0.f, 0.f};

  for (int k0 = 0; k0 < 1024; k0 += 64) {
    // stage A: f32 -> hi/lo bf16 (reg-staged split)
    #pragma unroll
    for (int p = 0; p < 8; ++p) {
      const int r = p * 16 + (tid >> 4);
      const int c = (tid & 15) * 4;
      float4 a = ld4(A + (size_t)r * 1024 + k0 + c);
      ushort4 h, l;
      h.x = f2bf(a.x); h.y = f2bf(a.y); h.z = f2bf(a.z); h.w = f2bf(a.w);
      l.x = f2bf(a.x - bf2f(h.x)); l.y = f2bf(a.y - bf2f(h.y));
      l.z = f2bf(a.z - bf2f(h.z)); l.w = f2bf(a.w - bf2f(h.w));
      *reinterpret_cast<ushort4*>(Ahi + r * 64 + c) = h;
      *reinterpret_cast<ushort4*>(Alo + r * 64 + c) = l;
    }
    // stage B (direct global->LDS), hi and (optionally) lo planes
    #pragma unroll
    for (int c = 0; c < 4; ++c) {
      const int r = srow + c * 8 + (lane >> 3);
      const int col = (lane & 7) * 8;
      __builtin_amdgcn_global_load_lds(
          (gu32*)(const void*)(Whi + (size_t)r * 1024 + k0 + col),
          (lu32*)(void*)(Bhi + (srow + c * 8) * 64), 16, 0, 0);
      if (three)
        __builtin_amdgcn_global_load_lds(
            (gu32*)(const void*)(Wlo + (size_t)r * 1024 + k0 + col),
            (lu32*)(void*)(Blo + (srow + c * 8) * 64), 16, 0, 0);
    }
    __syncthreads();
    #pragma unroll
    for (int kk = 0; kk < 2; ++kk) {
      short8 ah[4], al[4], bh[4], bl[4];
      #pragma unroll
      for (int m = 0; m < 4; ++m) {
        int row = wr * 64 + m * 16 + (lane & 15);
        ah[m] = *reinterpret_cast<const short8*>(Ahi + row * 64 + kk * 32 + (lane >> 4) * 8);
        if (three)
          al[m] = *reinterpret_cast<const short8*>(Alo + row * 64 + kk * 32 + (lane >> 4) * 8);
      }
      #pragma unroll
      for (int j = 0; j < 4; ++j) {
        int row = wc * 64 + j * 16 + (lane & 15);
        bh[j] = *reinterpret_cast<const short8*>(Bhi + row * 64 + kk * 32 + (lane >> 4) * 8);
        if (three)
          bl[j] = *reinterpret_cast<const short8*>(Blo + row * 64 + kk * 32 + (lane >> 4) * 8);
      }
      #pragma unroll
      for (int m = 0; m < 4; ++m)
        #pragma unroll
        for (int j = 0; j < 4; ++j) {
          acc[m][j] = __builtin_amdgcn_mfma_f32_16x16x32_bf16(ah[m], bh[j], acc[m][j], 0, 0, 0);
          if (three) {
            acc[m][j] = __builtin_amdgcn_mfma_f32_16x16x32_bf16(al[m], bh[j], acc[m][j], 0, 0, 0);
            acc[m][j] = __builtin_amdgcn_mfma_f32_16x16x32_bf16(ah[m], bl[j], acc[m][j], 0, 0, 0);
          }
        }
    }
    __syncthreads();
  }
  #pragma unroll
  for (int m = 0; m < 4; ++m)
    #pragma unroll
    for (int r = 0; r < 4; ++r) {
      const int row = wr * 64 + m * 16 + (lane >> 4) * 4 + r;
      #pragma unroll
      for (int j = 0; j < 4; ++j) {
        const int col = wc * 64 + j * 16 + (lane & 15);
        float v = acc[m][j][r];
        if (Cf) Cf[(size_t)(mt * 128 + row) * ldc + col0 + col] = v;
        else    Cb[(size_t)(mt * 128 + row) * ldc + col0 + col] = f2bf(v);
      }
    }
}

// ---------------------------------------------------------------- kernel C
// wfin[t][c] = -exp( yw[t] . w_w2[c] + w_b2[c] )  (f32)
__global__ __launch_bounds__(256) void kC(
    const float* __restrict__ yw, const float* __restrict__ w_w2,
    const float* __restrict__ w_b2, float* __restrict__ wfin) {
  __shared__ float th[32 * 68];
  const int tid = threadIdx.x;
  const int t0 = blockIdx.x * 32;
  for (int idx = tid; idx < 32 * 64; idx += 256) {
    int i = idx >> 6, j = idx & 63;
    th[i * 68 + j] = yw[(size_t)(t0 + i) * 64 + j];
  }
  __syncthreads();
  const int c = blockIdx.y * 256 + tid;
  float acc[32] = {};
  const float* w2 = w_w2 + (size_t)c * 64;
  for (int k = 0; k < 64; k += 4) {
    float4 wv = ld4(w2 + k);
    #pragma unroll
    for (int i = 0; i < 32; ++i) {
      float4 t4 = ld4(th + i * 68 + k);
      acc[i] += t4.x * wv.x + t4.y * wv.y + t4.z * wv.z + t4.w * wv.w;
    }
  }
  const float b = w_b2[c];
  #pragma unroll
  for (int i = 0; i < 32; ++i)
    wfin[(size_t)(t0 + i) * 512 + c] = -__expf(acc[i] + b);
}

// ---------------------------------------------------------------- kernel D1
// per (b,h,chunk): cumsum w; qe,ke,kw,decay; wkv=kw^T v; A; o_intra. All f32.
__global__ __launch_bounds__(256) void kD1(
    const float* __restrict__ rG, const float* __restrict__ kG,
    const float* __restrict__ vG, const float* __restrict__ wfin,
    const float* __restrict__ bonus, float* __restrict__ wkvG,
    float* __restrict__ decayG, float* __restrict__ qeG, float* __restrict__ oG) {
  extern __shared__ float sm[];
  float* wcl  = sm;                 // [32][129]
  float* kwl  = wcl + 32 * 129;     // [32][129]
  float* qeT  = kwl + 32 * 129;     // [128][36]
  float* keT  = qeT + 128 * 36;     // [128][36]
  float* vl   = keT + 128 * 36;     // [32][256]
  float* Al   = vl + 32 * 256;      // [32][32]
  float* diag = Al + 1024;          // [32]
  const int tid = threadIdx.x;
  const int bid = blockIdx.x;
  const int nc = bid & 63, h = (bid >> 6) & 3, b = bid >> 8;
  const int tb = b * Lc + nc * 32;

  for (int it = 0; it < 16; ++it) {
    int idx = it * 256 + tid;
    int c = idx >> 7, d = idx & 127;
    wcl[c * 129 + d] = wfin[(size_t)(tb + c) * 512 + h * 128 + d];
  }
  for (int base = tid * 4; base < 32 * 256; base += 1024) {
    int c = base >> 8, p = base & 255;
    st4(vl + c * 256 + p, ld4(vG + (size_t)(tb + c) * 1024 + h * 256 + p));
  }
  __syncthreads();
  if (tid < 128) {
    const int d = tid;
    float wv_[32];
    #pragma unroll
    for (int c = 0; c < 32; ++c) wv_[c] = wcl[c * 129 + d];
    float run = 0.f;
    #pragma unroll
    for (int c = 0; c < 32; ++c) { run += wv_[c]; wcl[c * 129 + d] = run; }
  } else if (tid < 160) {
    const int i = tid - 128;
    const float* qrow = rG + (size_t)(tb + i) * 512 + h * 128;
    const float* krow = kG + (size_t)(tb + i) * 512 + h * 128;
    const float* u = bonus + h * 128;
    float s0 = 0, s1 = 0, s2 = 0, s3 = 0;
    for (int d = 0; d < 128; d += 4) {
      s0 += qrow[d + 0] * u[d + 0] * krow[d + 0];
      s1 += qrow[d + 1] * u[d + 1] * krow[d + 1];
      s2 += qrow[d + 2] * u[d + 2] * krow[d + 2];
      s3 += qrow[d + 3] * u[d + 3] * krow[d + 3];
    }
    diag[i] = (s0 + s1) + (s2 + s3);
  }
  __syncthreads();
  for (int it = 0; it < 16; ++it) {
    int idx = it * 256 + tid;
    int c = idx >> 7, d = idx & 127;
    int t = tb + c;
    float q = rG[(size_t)t * 512 + h * 128 + d];
    float k = kG[(size_t)t * 512 + h * 128 + d];
    float wcc = wcl[c * 129 + d];
    float wcp = (c > 0) ? wcl[(c - 1) * 129 + d] : 0.f;
    float wlast = wcl[31 * 129 + d];
    float qe = q * __expf(wcp);
    float ke = k * __expf(-wcc);
    float kv = k * __expf(wlast - wcc);
    qeT[d * 36 + c] = qe;
    keT[d * 36 + c] = ke;
    kwl[c * 129 + d] = kv;
    qeG[(size_t)t * 512 + h * 128 + d] = qe;
    if (c == 31) decayG[(size_t)bid * 128 + d] = __expf(wlast);
  }
  __syncthreads();
  const int pid = tid & 63, wvx = tid >> 6;
  const int p4 = pid * 4;
  {  // wkv[d][p] = sum_c kw[c][d]*v[c][p]
    float* wkvB = wkvG + (size_t)bid * (128 * 256);
    for (int pp = 0; pp < 4; ++pp) {
      const int d0 = pp * 32 + wvx * 8;
      float4 acc[8];
      #pragma unroll
      for (int q = 0; q < 8; ++q) acc[q] = make_float4(0, 0, 0, 0);
      for (int c = 0; c < 32; ++c) {
        float4 v4 = ld4(vl + c * 256 + p4);
        #pragma unroll
        for (int q = 0; q < 8; ++q) {
          float s = kwl[c * 129 + d0 + q];
          acc[q].x += v4.x * s; acc[q].y += v4.y * s;
          acc[q].z += v4.z * s; acc[q].w += v4.w * s;
        }
      }
      #pragma unroll
      for (int q = 0; q < 8; ++q)
        st4(wkvB + (size_t)(d0 + q) * 256 + p4, acc[q]);
    }
  }
  {  // A[i][j]
    const int i4 = tid >> 3;
    const int j4 = (tid & 7) * 4;
    float4 accA = make_float4(0, 0, 0, 0);
    for (int d = 0; d < 128; ++d) {
      float qv = qeT[d * 36 + i4];
      float4 kv = ld4(keT + d * 36 + j4);
      accA.x += kv.x * qv; accA.y += kv.y * qv;
      accA.z += kv.z * qv; accA.w += kv.w * qv;
    }
    float av[4] = {accA.x, accA.y, accA.z, accA.w};
    #pragma unroll
    for (int jj = 0; jj < 4; ++jj) {
      int j = j4 + jj;
      Al[i4 * 32 + j] = (j < i4) ? av[jj] : ((j == i4) ? diag[i4] : 0.f);
    }
  }
  __syncthreads();
  {  // o_intra = A @ v
    float4 acc[8];
    #pragma unroll
    for (int q = 0; q < 8; ++q) acc[q] = make_float4(0, 0, 0, 0);
    for (int c = 0; c < 32; ++c) {
      float4 v4 = ld4(vl + c * 256 + p4);
      #pragma unroll
      for (int q = 0; q < 8; ++q) {
        float a = Al[(wvx * 8 + q) * 32 + c];
        acc[q].x += v4.x * a; acc[q].y += v4.y * a;
        acc[q].z += v4.z * a; acc[q].w += v4.w * a;
      }
    }
    #pragma unroll
    for (int q = 0; q < 8; ++q)
      st4(oG + (size_t)(tb + wvx * 8 + q) * 1024 + h * 256 + p4, acc[q]);
  }
}

// ---------------------------------------------------------------- kernel D2
// inter-chunk scan per (b,h,d)-row, in-place over f32 wkv; 4-deep prefetch.
__global__ __launch_bounds__(256) void kD2(float* __restrict__ wkvG,
                                           const float* __restrict__ decayG) {
  const int wvid = (blockIdx.x * 256 + threadIdx.x) >> 6;  // 0..1023
  const int lane = threadIdx.x & 63;
  const int p4 = lane * 4;
  const int d = wvid & 127;
  const int bh = wvid >> 7;
  float* base = wkvG + ((size_t)bh * 64 * 128 + d) * 256 + p4;
  const float* dbase = decayG + (size_t)bh * 64 * 128 + d;
  float4 kvb[4];
  float decb[4];
  #pragma unroll
  for (int i = 0; i < 4; ++i) {
    kvb[i] = ld4(base + (size_t)i * 32768);
    decb[i] = dbase[(size_t)i * 128];
  }
  float4 S = make_float4(0, 0, 0, 0);
  #pragma unroll
  for (int nc = 0; nc < 64; ++nc) {
    const int sl = nc & 3;
    float4 kv = kvb[sl];
    float dec = decb[sl];
    if (nc + 4 < 64) {
      kvb[sl] = ld4(base + (size_t)(nc + 4) * 32768);
      decb[sl] = dbase[(size_t)(nc + 4) * 128];
    }
    st4(base + (size_t)nc * 32768, S);
    S.x = S.x * dec + kv.x; S.y = S.y * dec + kv.y;
    S.z = S.z * dec + kv.z; S.w = S.w * dec + kv.w;
  }
}

// ---------------------------------------------------------------- kernel D3
// o += qe @ S_before per chunk (f32)
__global__ __launch_bounds__(256) void kD3(
    const float* __restrict__ qeG, const float* __restrict__ wkvG,
    float* __restrict__ oG) {
  __shared__ float qel[32 * 129];
  const int tid = threadIdx.x;
  const int bid = blockIdx.x;
  const int nc = bid & 63, h = (bid >> 6) & 3, b = bid >> 8;
  const int tb = b * Lc + nc * 32;
  for (int it = 0; it < 16; ++it) {
    int idx = it * 256 + tid;
    int c = idx >> 7, d = idx & 127;
    qel[c * 129 + d] = qeG[(size_t)(tb + c) * 512 + h * 128 + d];
  }
  __syncthreads();
  const int pid = tid & 63, wvx = tid >> 6;
  const int p4 = pid * 4;
  const float* Sb = wkvG + (size_t)bid * (128 * 256);
  float4 acc[8];
  #pragma unroll
  for (int q = 0; q < 8; ++q) acc[q] = make_float4(0, 0, 0, 0);
  for (int d = 0; d < 128; ++d) {
    float4 s4 = ld4(Sb + (size_t)d * 256 + p4);
    #pragma unroll
    for (int q = 0; q < 8; ++q) {
      float qv = qel[(wvx * 8 + q) * 129 + d];
      acc[q].x += s4.x * qv; acc[q].y += s4.y * qv;
      acc[q].z += s4.z * qv; acc[q].w += s4.w * qv;
    }
  }
  #pragma unroll
  for (int q = 0; q < 8; ++q) {
    float* op = oG + (size_t)(tb + wvx * 8 + q) * 1024 + h * 256 + p4;
    float4 cur = ld4(op);
    cur.x += acc[q].x; cur.y += acc[q].y; cur.z += acc[q].z; cur.w += acc[q].w;
    st4(op, cur);
  }
}

// ---------------------------------------------------------------- kernel E
// GroupNorm (per head, 256 ch) + swish gate -> bf16 gate buffer
__global__ __launch_bounds__(256) void kE(
    const float* __restrict__ oG, const u16* __restrict__ gG,
    const float* __restrict__ gn_w, const float* __restrict__ gn_b,
    u16* __restrict__ gate) {
  const int t = blockIdx.x;
  const int h = threadIdx.x >> 6, lane = threadIdx.x & 63;
  const int p4 = lane * 4;
  const int vd = h * 256 + p4;
  float4 v = ld4(oG + (size_t)t * 1024 + vd);
  float s = v.x + v.y + v.z + v.w;
  float ss = v.x * v.x + v.y * v.y + v.z * v.z + v.w * v.w;
  for (int m = 1; m < 64; m <<= 1) {
    s += __shfl_xor(s, m, 64);
    ss += __shfl_xor(ss, m, 64);
  }
  const float mean = s * (1.f / 256.f);
  const float var = ss * (1.f / 256.f) - mean * mean;
  const float rs = rsqrtf(var + 1e-5f);
  float4 gw = ld4(gn_w + vd), gb = ld4(gn_b + vd);
  float4 on;
  on.x = (v.x - mean) * rs * gw.x + gb.x;
  on.y = (v.y - mean) * rs * gw.y + gb.y;
  on.z = (v.z - mean) * rs * gw.z + gb.z;
  on.w = (v.w - mean) * rs * gw.w + gb.w;
  ushort4 g4 = *reinterpret_cast<const ushort4*>(gG + (size_t)t * 1024 + vd);
  float gx = bf2f(g4.x), gy = bf2f(g4.y), gz = bf2f(g4.z), gw_ = bf2f(g4.w);
  float4 sw;
  sw.x = gx / (1.f + __expf(-gx));
  sw.y = gy / (1.f + __expf(-gy));
  sw.z = gz / (1.f + __expf(-gz));
  sw.w = gw_ / (1.f + __expf(-gw_));
  ushort4 ob;
  ob.x = f2bf(on.x * sw.x); ob.y = f2bf(on.y * sw.y);
  ob.z = f2bf(on.z * sw.z); ob.w = f2bf(on.w * sw.w);
  *reinterpret_cast<ushort4*>(gate + (size_t)t * 1024 + vd) = ob;
}

// ---------------------------------------------------------------- kernel F
// out = gate(bf16) @ o_w^T(bf16), single-pass MFMA, f32 out
__global__ __launch_bounds__(256) void kF(
    const u16* __restrict__ gate, const u16* __restrict__ owb,
    float* __restrict__ out) {
  __shared__ __align__(16) u16 Abuf[128 * 64];
  __shared__ __align__(16) u16 Bbuf[128 * 64];
  const int mt = blockIdx.x, nt = blockIdx.y;
  const u16* A = gate + (size_t)mt * 128 * 1024;
  const u16* W = owb + (size_t)nt * 128 * 1024;
  float* C = out + (size_t)mt * 128 * 1024 + nt * 128;
  const int tid = threadIdx.x;
  const int lane = tid & 63;
  const int wv = tid >> 6;
  const int wr = wv >> 1, wc = wv & 1;
  const int srow = wv * 32;
  f32x4 acc[4][4];
  #pragma unroll
  for (int i = 0; i < 4; ++i)
    #pragma unroll
    for (int j = 0; j < 4; ++j) acc[i][j] = {0.f, 0.f, 0.f, 0.f};
  for (int k0 = 0; k0 < 1024; k0 += 64) {
    #pragma unroll
    for (int c = 0; c < 4; ++c) {
      const int r = srow + c * 8 + (lane >> 3);
      const int col = (lane & 7) * 8;
      __builtin_amdgcn_global_load_lds(
          (gu32*)(const void*)(A + (size_t)r * 1024 + k0 + col),
          (lu32*)(void*)(Abuf + (srow + c * 8) * 64), 16, 0, 0);
      __builtin_amdgcn_global_load_lds(
          (gu32*)(const void*)(W + (size_t)r * 1024 + k0 + col),
          (lu32*)(void*)(Bbuf + (srow + c * 8) * 64), 16, 0, 0);
    }
    __syncthreads();
    #pragma unroll
    for (int kk = 0; kk < 2; ++kk) {
      short8 af[4], bfr[4];
      #pragma unroll
      for (int m = 0; m < 4; ++m) {
        int row = wr * 64 + m * 16 + (lane & 15);
        af[m] = *reinterpret_cast<const short8*>(Abuf + row * 64 + kk * 32 + (lane >> 4) * 8);
      }
      #pragma unroll
      for (int j = 0; j < 4; ++j) {
        int row = wc * 64 + j * 16 + (lane & 15);
        bfr[j] = *reinterpret_cast<const short8*>(Bbuf + row * 64 + kk * 32 + (lane >> 4) * 8);
      }
      #pragma unroll
      for (int m = 0; m < 4; ++m)
        #pragma unroll
        for (int j = 0; j < 4; ++j)
          acc[m][j] = __builtin_amdgcn_mfma_f32_16x16x32_bf16(af[m], bfr[j], acc[m][j], 0, 0, 0);
    }
    __syncthreads();
  }
  #pragma unroll
  for (int m = 0; m < 4; ++m)
    #pragma unroll
    for (int r = 0; r < 4; ++r) {
      const int row = wr * 64 + m * 16 + (lane >> 4) * 4 + r;
      #pragma unroll
      for (int j = 0; j < 4; ++j) {
        const int col = wc * 64 + j * 16 + (lane & 15);
        C[(size_t)row * 1024 + col] = acc[m][j][r];
      }
    }
}

}  // namespace

extern "C" void kernel_launch(void* const* d_in, const int* in_sizes, int n_in,
                              void* d_out, int out_size, void* d_ws, size_t ws_size,
                              hipStream_t stream) {
  (void)in_sizes; (void)n_in; (void)out_size;
  if (ws_size < WS_NEED) return;

  const float* x      = (const float*)d_in[0];
  const float* x0_mu  = (const float*)d_in[1];
  const float* x0_w   = (const float*)d_in[2];
  const float* x2_w   = (const float*)d_in[3];
  const float* x_bias = (const float*)d_in[4];
  const float* r_w    = (const float*)d_in[5];
  const float* w_w1   = (const float*)d_in[6];
  const float* w_w2   = (const float*)d_in[7];
  const float* w_b2   = (const float*)d_in[8];
  const float* k_w    = (const float*)d_in[9];
  const float* v_w    = (const float*)d_in[10];
  const float* g_w    = (const float*)d_in[11];
  const float* bonus  = (const float*)d_in[12];
  const float* gn_w   = (const float*)d_in[13];
  const float* gn_b   = (const float*)d_in[14];
  const float* o_w    = (const float*)d_in[15];
  float* out = (float*)d_out;
  char* ws = (char*)d_ws;

  float* wkvG   = (float*)(ws + OFF_WKV);
  float* xm0    = (float*)(ws + OFF_XM0);
  float* delta  = (float*)(ws + OFF_DELTA);
  float* t160   = (float*)(ws + OFF_T160);
  float* xmw    = (float*)(ws + OFF_XMW);
  u16*   Wsp    = (u16*)(ws + OFF_WSP);
  float* yw     = (float*)(ws + OFF_YW);
  float* xmf    = (float*)(ws + OFF_XMF);
  float* oG     = (float*)(ws + OFF_OO);
  float* qeG    = (float*)(ws + OFF_QE);
  float* decayG = (float*)(ws + OFF_DECAY);
  u16*   gate   = (u16*)(ws + OFF_GATE);
  float* rG     = (float*)(ws + OFF_RG);
  float* kG     = (float*)(ws + OFF_KG);
  float* vG     = (float*)(ws + OFF_VG);
  u16*   gG     = (u16*)(ws + OFF_GG);
  float* wfin   = (float*)(ws + OFF_WFIN);
  u16*   owb    = (u16*)(ws + OFF_OWB);
  u16*   Whi    = Wsp;
  u16*   Wlo    = Wsp + WLO_OFF_E;

  const size_t ldsD1 = (size_t)(32 * 129 * 2 + 128 * 36 * 2 + 32 * 256 + 1024 + 32) * 4;

  kW   <<<dim3(4096),      dim3(256), 0, stream>>>(r_w, k_w, v_w, g_w, o_w, Whi, Wlo, owb);
  kA1  <<<dim3(4096),      dim3(256), 0, stream>>>(x, x0_mu, xm0, delta);
  kA2  <<<dim3(32, 5),     dim3(256), 0, stream>>>(xm0, x0_w, t160);
  kA2mf<<<dim3(64, 16),    dim3(256), 0, stream>>>(t160, x2_w, x_bias, xm0, delta,
                                                   x0_mu, xmf, xmw);
  kWL  <<<dim3(128),       dim3(256), 0, stream>>>(xmw, w_w1, yw);
  kB   <<<dim3(32, 24),    dim3(256), 0, stream>>>(xmf, Wsp, rG, kG, vG, gG);
  kC   <<<dim3(128, 2),    dim3(256), 0, stream>>>(yw, w_w2, w_b2, wfin);
  kD1  <<<dim3(512),       dim3(256), ldsD1, stream>>>(rG, kG, vG, wfin, bonus,
                                                       wkvG, decayG, qeG, oG);
  kD2  <<<dim3(256),       dim3(256), 0, stream>>>(wkvG, decayG);
  kD3  <<<dim3(512),       dim3(256), 0, stream>>>(qeG, wkvG, oG);
  kE   <<<dim3(4096),      dim3(256), 0, stream>>>(oG, gG, gn_w, gn_b, gate);
  kF   <<<dim3(32, 8),     dim3(256), 0, stream>>>(gate, owb, out);
}

// Round 5
// 444.241 us; speedup vs baseline: 2.9194x; 1.2341x over previous
//
#include <hip/hip_runtime.h>

// RWKV6Attention forward — round 5: kD1 restructure (2 blocks/CU, conflict-free
// LDS, keT eliminated), kB pure-gload_lds bf16x3 with pre-split A planes,
// kD2 2-waves/row. All D-chain numerics f32 (R4-proven precision).

#define DEVI __device__ __forceinline__

namespace {

typedef unsigned short u16;
typedef unsigned int u32;
typedef __attribute__((ext_vector_type(8))) short short8;   // 8 bf16 (4 VGPRs)
typedef __attribute__((ext_vector_type(4))) float f32x4;

typedef __attribute__((address_space(1))) const u32 gu32;
typedef __attribute__((address_space(3))) u32 lu32;

constexpr int Lc = 2048;
constexpr int Tc = 4096;   // B*L

// ---- workspace layout (byte offsets), lifetime-safe aliasing.
constexpr size_t OFF_WKV   = 0;            // f32 [512][128][256] = 67,108,864 (kD1+)
constexpr size_t OFF_XM0   = 0;            // f32 [T][1024]  dead after kA2mf
constexpr size_t OFF_DELTA = 16777216;     // f32 [T][1024]  dead after kA2mf
constexpr size_t OFF_T160  = 33554432;     // f32 [T][160]   dead after kA2mf
constexpr size_t OFF_XMW   = 36175872;     // f32 [T][1024]  dead after kWL
constexpr size_t OFF_YW    = 52953088;     // f32 [T][64]    dead after kC
constexpr size_t OFF_XMHI  = 67108864;     // bf16 [4][T][1024] dead after kB
constexpr size_t OFF_WFIN  = 67108864;     //   f32 [T][512]  (kC -> kD1)
constexpr size_t OFF_GATE  = 75497472;     //   bf16 [T][1024] (kE -> kF)
constexpr size_t OFF_XMLO  = 100663296;    // bf16 [3][T][1024] dead after kB
constexpr size_t OFF_QE    = 100663296;    //   f32 [T][512]   (kD1 -> kD3)
constexpr size_t OFF_OO    = 109051904;    //   f32 [T][1024]  (kD1 -> kE)
constexpr size_t OFF_WHI   = 125829120;    // bf16 [3072][1024] dead after kB
constexpr size_t OFF_WLO   = 132120576;    // bf16 [2048][1024] dead after kB
constexpr size_t OFF_DECAY = 132120576;    //   f32 [512][128]  (kD1 -> kD2)
constexpr size_t OFF_OWB   = 136314880;    // bf16 [1024][1024] (kW -> kF)
constexpr size_t OFF_RG    = 138412032;    // f32 [T][512]
constexpr size_t OFF_KG    = 146800640;    // f32 [T][512]
constexpr size_t OFF_VG    = 155189248;    // f32 [T][1024]
constexpr size_t OFF_GG    = 171966464;    // bf16 [T][1024]
constexpr size_t WS_NEED   = 180355072;

DEVI float4 ld4(const float* p) { return *reinterpret_cast<const float4*>(p); }
DEVI void   st4(float* p, float4 v) { *reinterpret_cast<float4*>(p) = v; }
DEVI float2 ld2(const float* p) { return *reinterpret_cast<const float2*>(p); }
DEVI void   st2(float* p, float2 v) { *reinterpret_cast<float2*>(p) = v; }
DEVI u16 f2bf(float f) {
  u32 u = __float_as_uint(f);
  return (u16)((u + 0x7FFFu + ((u >> 16) & 1u)) >> 16);
}
DEVI float bf2f(u16 u) { return __uint_as_float((u32)u << 16); }

// ---------------------------------------------------------------- kernel W
// proj weights -> Whi[3072][1024] (+ Wlo for r,k,v rows), o_w -> owb bf16.
__global__ void kW(const float* __restrict__ r_w, const float* __restrict__ k_w,
                   const float* __restrict__ v_w, const float* __restrict__ g_w,
                   const float* __restrict__ o_w, u16* __restrict__ Whi,
                   u16* __restrict__ Wlo, u16* __restrict__ owb) {
  const size_t i = ((size_t)blockIdx.x * 256 + threadIdx.x) * 4;
  if (i < 3145728) {
    const float* src = (i < 524288)  ? r_w + i
                     : (i < 1048576) ? k_w + (i - 524288)
                     : (i < 2097152) ? v_w + (i - 1048576)
                                     : g_w + (i - 2097152);
    float4 v = ld4(src);
    ushort4 h;
    h.x = f2bf(v.x); h.y = f2bf(v.y); h.z = f2bf(v.z); h.w = f2bf(v.w);
    *reinterpret_cast<ushort4*>(Whi + i) = h;
    if (i < 2097152) {
      ushort4 l;
      l.x = f2bf(v.x - bf2f(h.x)); l.y = f2bf(v.y - bf2f(h.y));
      l.z = f2bf(v.z - bf2f(h.z)); l.w = f2bf(v.w - bf2f(h.w));
      *reinterpret_cast<ushort4*>(Wlo + i) = l;
    }
  } else {
    float4 v = ld4(o_w + (i - 3145728));
    ushort4 h;
    h.x = f2bf(v.x); h.y = f2bf(v.y); h.z = f2bf(v.z); h.w = f2bf(v.w);
    *reinterpret_cast<ushort4*>(owb + (i - 3145728)) = h;
  }
}

// ---------------------------------------------------------------- kernel A1
__global__ void kA1(const float* __restrict__ x, const float* __restrict__ x0_mu,
                    float* __restrict__ xm0, float* __restrict__ delta) {
  const size_t i4 = (size_t)blockIdx.x * 256 + threadIdx.x;
  const int t = (int)(i4 >> 8);
  const int h4 = (int)(i4 & 255) * 4;
  float4 xv = ld4(x + (size_t)t * 1024 + h4);
  float4 xp = make_float4(0.f, 0.f, 0.f, 0.f);
  if (t & (Lc - 1)) xp = ld4(x + (size_t)(t - 1) * 1024 + h4);
  float4 mu = ld4(x0_mu + h4);
  float4 d;
  d.x = xp.x - xv.x; d.y = xp.y - xv.y; d.z = xp.z - xv.z; d.w = xp.w - xv.w;
  st4(delta + (size_t)t * 1024 + h4, d);
  float4 m0;
  m0.x = xv.x + d.x * mu.x; m0.y = xv.y + d.y * mu.y;
  m0.z = xv.z + d.z * mu.z; m0.w = xv.w + d.w * mu.w;
  st4(xm0 + (size_t)t * 1024 + h4, m0);
}

// ---------------------------------------------------------------- kernel A2
// t160[T][160] = tanh(xm0 @ x0_w^T), fp32
__global__ __launch_bounds__(256) void kA2(
    const float* __restrict__ xm0, const float* __restrict__ x0_w,
    float* __restrict__ t160) {
  __shared__ float As[128 * 33];
  __shared__ float Ws[32 * 33];
  const int tid = threadIdx.x;
  const int m0 = blockIdx.x * 128;
  const int n0 = blockIdx.y * 32;
  const int trow = (tid >> 3) * 4;
  const int tn4 = (tid & 7) * 4;
  float acc[4][4] = {};
  for (int k0 = 0; k0 < 1024; k0 += 32) {
    __syncthreads();
    #pragma unroll
    for (int c = 0; c < 4; ++c) {
      int r = c * 32 + (tid >> 3);
      int col = (tid & 7) * 4;
      float4 a4 = ld4(xm0 + (size_t)(m0 + r) * 1024 + k0 + col);
      As[r * 33 + col + 0] = a4.x; As[r * 33 + col + 1] = a4.y;
      As[r * 33 + col + 2] = a4.z; As[r * 33 + col + 3] = a4.w;
    }
    {
      int r = tid >> 3;
      int col = (tid & 7) * 4;
      float4 w4 = ld4(x0_w + (size_t)(n0 + r) * 1024 + k0 + col);
      Ws[r * 33 + col + 0] = w4.x; Ws[r * 33 + col + 1] = w4.y;
      Ws[r * 33 + col + 2] = w4.z; Ws[r * 33 + col + 3] = w4.w;
    }
    __syncthreads();
    #pragma unroll
    for (int kk = 0; kk < 32; ++kk) {
      float a[4], w[4];
      #pragma unroll
      for (int i = 0; i < 4; ++i) a[i] = As[(trow + i) * 33 + kk];
      #pragma unroll
      for (int j = 0; j < 4; ++j) w[j] = Ws[(tn4 + j) * 33 + kk];
      #pragma unroll
      for (int i = 0; i < 4; ++i)
        #pragma unroll
        for (int j = 0; j < 4; ++j) acc[i][j] += a[i] * w[j];
    }
  }
  #pragma unroll
  for (int i = 0; i < 4; ++i)
    #pragma unroll
    for (int j = 0; j < 4; ++j)
      t160[(size_t)(m0 + trow + i) * 160 + n0 + tn4 + j] = tanhf(acc[i][j]);
}

// ---------------------------------------------------------------- kernel A2mf
// fused mix + lerp; writes bf16 hi/lo planes (r,k,v), bf16 hi (g), f32 xmw (w).
__global__ __launch_bounds__(256) void kA2mf(
    const float* __restrict__ t160G, const float* __restrict__ x2_w,
    const float* __restrict__ x_bias, const float* __restrict__ xm0,
    const float* __restrict__ delta, const float* __restrict__ x0_mu,
    u16* __restrict__ xmhi, u16* __restrict__ xmlo, float* __restrict__ xmw) {
  __shared__ float As[64 * 33];
  __shared__ float Ws[64 * 33];
  const int tid = threadIdx.x;
  const int m0 = blockIdx.x * 64, h0 = blockIdx.y * 64;
  const int rm = (tid >> 4) * 4, cn = (tid & 15) * 4;
  float4 xm4[4], dv4[4];
  #pragma unroll
  for (int i = 0; i < 4; ++i) {
    xm4[i] = ld4(xm0 + (size_t)(m0 + rm + i) * 1024 + h0 + cn);
    dv4[i] = ld4(delta + (size_t)(m0 + rm + i) * 1024 + h0 + cn);
  }
  const float4 mu4 = ld4(x0_mu + h0 + cn);
  for (int n = 0; n < 5; ++n) {
    __syncthreads();
    #pragma unroll
    for (int c = 0; c < 2; ++c) {
      int r = c * 32 + (tid >> 3);
      int col = (tid & 7) * 4;
      float4 a4 = ld4(t160G + (size_t)(m0 + r) * 160 + n * 32 + col);
      As[r * 33 + col + 0] = a4.x; As[r * 33 + col + 1] = a4.y;
      As[r * 33 + col + 2] = a4.z; As[r * 33 + col + 3] = a4.w;
      float4 w4 = ld4(x2_w + (size_t)(h0 + r) * 160 + n * 32 + col);
      Ws[r * 33 + col + 0] = w4.x; Ws[r * 33 + col + 1] = w4.y;
      Ws[r * 33 + col + 2] = w4.z; Ws[r * 33 + col + 3] = w4.w;
    }
    __syncthreads();
    float acc[4][4] = {};
    #pragma unroll
    for (int kk = 0; kk < 32; ++kk) {
      float a[4], w[4];
      #pragma unroll
      for (int i = 0; i < 4; ++i) a[i] = As[(rm + i) * 33 + kk];
      #pragma unroll
      for (int j = 0; j < 4; ++j) w[j] = Ws[(cn + j) * 33 + kk];
      #pragma unroll
      for (int i = 0; i < 4; ++i)
        #pragma unroll
        for (int j = 0; j < 4; ++j) acc[i][j] += a[i] * w[j];
    }
    const float4 b4 = ld4(x_bias + n * 1024 + h0 + cn);
    const int pi = (n == 0) ? 0 : (n == 2) ? 1 : (n == 3) ? 2 : 3;  // n==4 -> 3
    #pragma unroll
    for (int i = 0; i < 4; ++i) {
      float4 o;
      o.x = xm4[i].x + dv4[i].x * (acc[i][0] + b4.x - mu4.x);
      o.y = xm4[i].y + dv4[i].y * (acc[i][1] + b4.y - mu4.y);
      o.z = xm4[i].z + dv4[i].z * (acc[i][2] + b4.z - mu4.z);
      o.w = xm4[i].w + dv4[i].w * (acc[i][3] + b4.w - mu4.w);
      if (n == 1) {
        st4(xmw + (size_t)(m0 + rm + i) * 1024 + h0 + cn, o);
      } else {
        ushort4 h;
        h.x = f2bf(o.x); h.y = f2bf(o.y); h.z = f2bf(o.z); h.w = f2bf(o.w);
        *reinterpret_cast<ushort4*>(xmhi + ((size_t)pi * Tc + m0 + rm + i) * 1024 + h0 + cn) = h;
        if (n != 4) {
          ushort4 l;
          l.x = f2bf(o.x - bf2f(h.x)); l.y = f2bf(o.y - bf2f(h.y));
          l.z = f2bf(o.z - bf2f(h.z)); l.w = f2bf(o.w - bf2f(h.w));
          *reinterpret_cast<ushort4*>(xmlo + ((size_t)pi * Tc + m0 + rm + i) * 1024 + h0 + cn) = l;
        }
      }
    }
  }
}

// ---------------------------------------------------------------- kernel WL
// y_w[T][64] = tanh(xmw @ w_w1^T), fp32
__global__ __launch_bounds__(256) void kWL(
    const float* __restrict__ xmw, const float* __restrict__ w_w1,
    float* __restrict__ yw) {
  __shared__ float As[32 * 33];
  __shared__ float Ws[64 * 33];
  const int tid = threadIdx.x;
  const int t0 = blockIdx.x * 32;
  const int rg = tid >> 5;
  const int cg = tid & 31;
  float acc[4][2] = {};
  for (int k0 = 0; k0 < 1024; k0 += 32) {
    __syncthreads();
    {
      int r = tid >> 3, c4 = (tid & 7) * 4;
      float4 a4 = ld4(xmw + (size_t)(t0 + r) * 1024 + k0 + c4);
      As[r * 33 + c4 + 0] = a4.x; As[r * 33 + c4 + 1] = a4.y;
      As[r * 33 + c4 + 2] = a4.z; As[r * 33 + c4 + 3] = a4.w;
    }
    #pragma unroll
    for (int c = 0; c < 2; ++c) {
      int r = c * 32 + (tid >> 3), c4 = (tid & 7) * 4;
      float4 w4 = ld4(w_w1 + (size_t)r * 1024 + k0 + c4);
      Ws[r * 33 + c4 + 0] = w4.x; Ws[r * 33 + c4 + 1] = w4.y;
      Ws[r * 33 + c4 + 2] = w4.z; Ws[r * 33 + c4 + 3] = w4.w;
    }
    __syncthreads();
    #pragma unroll
    for (int kk = 0; kk < 32; ++kk) {
      float a[4];
      #pragma unroll
      for (int i = 0; i < 4; ++i) a[i] = As[(rg * 4 + i) * 33 + kk];
      float w0 = Ws[cg * 33 + kk], w1 = Ws[(cg + 32) * 33 + kk];
      #pragma unroll
      for (int i = 0; i < 4; ++i) { acc[i][0] += a[i] * w0; acc[i][1] += a[i] * w1; }
    }
  }
  #pragma unroll
  for (int i = 0; i < 4; ++i) {
    yw[(size_t)(t0 + rg * 4 + i) * 64 + cg]      = tanhf(acc[i][0]);
    yw[(size_t)(t0 + rg * 4 + i) * 64 + cg + 32] = tanhf(acc[i][1]);
  }
}

// -------------------------------------------- bf16x3 MFMA GEMM, pre-split A
__global__ __launch_bounds__(256) void kB(
    const u16* __restrict__ xmhi, const u16* __restrict__ xmlo,
    const u16* __restrict__ Whi, const u16* __restrict__ Wlo,
    float* __restrict__ rG, float* __restrict__ kG,
    float* __restrict__ vG, u16* __restrict__ gG) {
  __shared__ __align__(16) u16 sAh[128 * 64];
  __shared__ __align__(16) u16 sAl[128 * 64];
  __shared__ __align__(16) u16 sBh[128 * 64];
  __shared__ __align__(16) u16 sBl[128 * 64];
  const int mt = blockIdx.x, nt = blockIdx.y;
  int plane, col0, ldc;
  float* Cf = nullptr;
  u16* Cb = nullptr;
  bool three = true;
  if (nt < 4)       { plane = 0; Cf = rG; ldc = 512;  col0 = nt * 128; }
  else if (nt < 8)  { plane = 1; Cf = kG; ldc = 512;  col0 = (nt - 4) * 128; }
  else if (nt < 16) { plane = 2; Cf = vG; ldc = 1024; col0 = (nt - 8) * 128; }
  else              { plane = 3; Cb = gG; ldc = 1024; col0 = (nt - 16) * 128; three = false; }
  const u16* Ah = xmhi + ((size_t)plane * Tc + (size_t)mt * 128) * 1024;
  const u16* Al = xmlo + ((size_t)plane * Tc + (size_t)mt * 128) * 1024;
  const u16* Bh = Whi + (size_t)nt * 128 * 1024;
  const u16* Bl = Wlo + (size_t)nt * 128 * 1024;

  const int tid = threadIdx.x;
  const int lane = tid & 63;
  const int wv = tid >> 6;
  const int wr = wv >> 1, wc = wv & 1;
  const int srow = wv * 32;
  f32x4 acc[4][4];
  #pragma unroll
  for (int i = 0; i < 4; ++i)
    #pragma unroll
    for (int j = 0; j < 4; ++j) acc[i][j] = {0.f, 0.f, 0.f, 0.f};

  for (int k0 = 0; k0 < 1024; k0 += 64) {
    #pragma unroll
    for (int c = 0; c < 4; ++c) {
      const int r = srow + c * 8 + (lane >> 3);
      const int col = (lane & 7) * 8;
      const size_t goff = (size_t)r * 1024 + k0 + col;
      const int loff = (srow + c * 8) * 64;
      __builtin_amdgcn_global_load_lds((gu32*)(const void*)(Ah + goff),
                                       (lu32*)(void*)(sAh + loff), 16, 0, 0);
      __builtin_amdgcn_global_load_lds((gu32*)(const void*)(Bh + goff),
                                       (lu32*)(void*)(sBh + loff), 16, 0, 0);
      if (three) {
        __builtin_amdgcn_global_load_lds((gu32*)(const void*)(Al + goff),
                                         (lu32*)(void*)(sAl + loff), 16, 0, 0);
        __builtin_amdgcn_global_load_lds((gu32*)(const void*)(Bl + goff),
                                         (lu32*)(void*)(sBl + loff), 16, 0, 0);
      }
    }
    __syncthreads();
    #pragma unroll
    for (int kk = 0; kk < 2; ++kk) {
      short8 ah[4], al[4], bh[4], bl[4];
      #pragma unroll
      for (int m = 0; m < 4; ++m) {
        int row = wr * 64 + m * 16 + (lane & 15);
        ah[m] = *reinterpret_cast<const short8*>(sAh + row * 64 + kk * 32 + (lane >> 4) * 8);
        if (three)
          al[m] = *reinterpret_cast<const short8*>(sAl + row * 64 + kk * 32 + (lane >> 4) * 8);
      }
      #pragma unroll
      for (int j = 0; j < 4; ++j) {
        int row = wc * 64 + j * 16 + (lane & 15);
        bh[j] = *reinterpret_cast<const short8*>(sBh + row * 64 + kk * 32 + (lane >> 4) * 8);
        if (three)
          bl[j] = *reinterpret_cast<const short8*>(sBl + row * 64 + kk * 32 + (lane >> 4) * 8);
      }
      #pragma unroll
      for (int m = 0; m < 4; ++m)
        #pragma unroll
        for (int j = 0; j < 4; ++j) {
          acc[m][j] = __builtin_amdgcn_mfma_f32_16x16x32_bf16(ah[m], bh[j], acc[m][j], 0, 0, 0);
          if (three) {
            acc[m][j] = __builtin_amdgcn_mfma_f32_16x16x32_bf16(al[m], bh[j], acc[m][j], 0, 0, 0);
            acc[m][j] = __builtin_amdgcn_mfma_f32_16x16x32_bf16(ah[m], bl[j], acc[m][j], 0, 0, 0);
          }
        }
    }
    __syncthreads();
  }
  #pragma unroll
  for (int m = 0; m < 4; ++m)
    #pragma unroll
    for (int r = 0; r < 4; ++r) {
      const int row = wr * 64 + m * 16 + (lane >> 4) * 4 + r;
      #pragma unroll
      for (int j = 0; j < 4; ++j) {
        const int col = wc * 64 + j * 16 + (lane & 15);
        float v = acc[m][j][r];
        if (Cf) Cf[(size_t)(mt * 128 + row) * ldc + col0 + col] = v;
        else    Cb[(size_t)(mt * 128 + row) * ldc + col0 + col] = f2bf(v);
      }
    }
}

// ---------------------------------------------------------------- kernel C
__global__ __launch_bounds__(256) void kC(
    const float* __restrict__ yw, const float* __restrict__ w_w2,
    const float* __restrict__ w_b2, float* __restrict__ wfin) {
  __shared__ float th[32 * 68];
  const int tid = threadIdx.x;
  const int t0 = blockIdx.x * 32;
  for (int idx = tid; idx < 32 * 64; idx += 256) {
    int i = idx >> 6, j = idx & 63;
    th[i * 68 + j] = yw[(size_t)(t0 + i) * 64 + j];
  }
  __syncthreads();
  const int c = blockIdx.y * 256 + tid;
  float acc[32] = {};
  const float* w2 = w_w2 + (size_t)c * 64;
  for (int k = 0; k < 64; k += 4) {
    float4 wv = ld4(w2 + k);
    #pragma unroll
    for (int i = 0; i < 32; ++i) {
      float4 t4 = ld4(th + i * 68 + k);
      acc[i] += t4.x * wv.x + t4.y * wv.y + t4.z * wv.z + t4.w * wv.w;
    }
  }
  const float b = w_b2[c];
  #pragma unroll
  for (int i = 0; i < 32; ++i)
    wfin[(size_t)(t0 + i) * 512 + c] = -__expf(acc[i] + b);
}

// ---------------------------------------------------------------- kernel D1
// 512 threads. LDS (70.9 KB, 2 blocks/CU):
//   vl[32][256] (first 4128 floats alias wcl[32][129]) | kwT[128][33] |
//   qeT[128][33] (holds qe2 = qe*exp(-wlast)) | Al[32][33] | diag[32]
// ke eliminated: A = sum_d qe2[i,d]*kv[j,d].
__global__ __launch_bounds__(512) void kD1(
    const float* __restrict__ rG, const float* __restrict__ kG,
    const float* __restrict__ vG, const float* __restrict__ wfin,
    const float* __restrict__ bonus, float* __restrict__ wkvG,
    float* __restrict__ decayG, float* __restrict__ qeG, float* __restrict__ oG) {
  extern __shared__ float sm[];
  float* vl   = sm;                 // [32][256] = 8192
  float* wcl  = sm;                 // [32][129] alias (dead before vl load)
  float* kwT  = sm + 8192;          // [128][33] = 4224
  float* qeT  = kwT + 4224;         // [128][33] = 4224
  float* Al   = qeT + 4224;         // [32][33]  = 1056
  float* diag = Al + 1056;          // [32]
  const int tid = threadIdx.x;
  const int bid = blockIdx.x;
  const int nc = bid & 63, h = (bid >> 6) & 3, b = bid >> 8;
  const int tb = b * Lc + nc * 32;

  // phase 1: wfin -> wcl
  #pragma unroll
  for (int it = 0; it < 2; ++it) {
    int idx = it * 512 + tid;          // 0..1023 float4s
    int c = idx >> 5, d4 = (idx & 31) * 4;
    float4 w4 = ld4(wfin + (size_t)(tb + c) * 512 + h * 128 + d4);
    wcl[c * 129 + d4 + 0] = w4.x; wcl[c * 129 + d4 + 1] = w4.y;
    wcl[c * 129 + d4 + 2] = w4.z; wcl[c * 129 + d4 + 3] = w4.w;
  }
  __syncthreads();
  // phase 2: cumsum along chunk (tid<128) + diag (tid 128..159)
  if (tid < 128) {
    const int d = tid;
    float wv_[32];
    #pragma unroll
    for (int c = 0; c < 32; ++c) wv_[c] = wcl[c * 129 + d];
    float run = 0.f;
    #pragma unroll
    for (int c = 0; c < 32; ++c) { run += wv_[c]; wcl[c * 129 + d] = run; }
  } else if (tid < 160) {
    const int i = tid - 128;
    const float* qrow = rG + (size_t)(tb + i) * 512 + h * 128;
    const float* krow = kG + (size_t)(tb + i) * 512 + h * 128;
    const float* u = bonus + h * 128;
    float s0 = 0, s1 = 0, s2 = 0, s3 = 0;
    for (int d = 0; d < 128; d += 4) {
      s0 += qrow[d + 0] * u[d + 0] * krow[d + 0];
      s1 += qrow[d + 1] * u[d + 1] * krow[d + 1];
      s2 += qrow[d + 2] * u[d + 2] * krow[d + 2];
      s3 += qrow[d + 3] * u[d + 3] * krow[d + 3];
    }
    diag[i] = (s0 + s1) + (s2 + s3);
  }
  __syncthreads();
  // phase 3: elementwise -> qeT(qe2), kwT(kv), qeG, decay
  #pragma unroll
  for (int it = 0; it < 8; ++it) {
    int idx = it * 512 + tid;
    int c = idx >> 7, d = idx & 127;
    int t = tb + c;
    float q = rG[(size_t)t * 512 + h * 128 + d];
    float k = kG[(size_t)t * 512 + h * 128 + d];
    float wcc = wcl[c * 129 + d];
    float wcp = (c > 0) ? wcl[(c - 1) * 129 + d] : 0.f;
    float wlast = wcl[31 * 129 + d];
    float qe = q * __expf(wcp);
    qeT[d * 33 + c] = q * __expf(wcp - wlast);   // qe2
    kwT[d * 33 + c] = k * __expf(wlast - wcc);   // kv
    qeG[(size_t)t * 512 + h * 128 + d] = qe;
    if (c == 31) decayG[(size_t)bid * 128 + d] = __expf(wlast);
  }
  __syncthreads();  // wcl reads done; qeT/kwT visible
  // phase 4: load v into vl (overwrites wcl)
  #pragma unroll
  for (int it = 0; it < 4; ++it) {
    int idx = it * 512 + tid;           // 0..2047 float4s
    int c = idx >> 6, p4 = (idx & 63) * 4;
    st4(vl + c * 256 + p4, ld4(vG + (size_t)(tb + c) * 1024 + h * 256 + p4));
  }
  __syncthreads();
  const int pid = tid & 63, wvx = tid >> 6;
  const int p4 = pid * 4;
  // phase 5: wkv[d][p] = sum_c kv[c][d]*v[c][p]
  {
    float* wkvB = wkvG + (size_t)bid * (128 * 256);
    #pragma unroll
    for (int pp = 0; pp < 2; ++pp) {
      const int d0 = pp * 64 + wvx * 8;
      float4 acc[8];
      #pragma unroll
      for (int q = 0; q < 8; ++q) acc[q] = make_float4(0, 0, 0, 0);
      for (int c = 0; c < 32; ++c) {
        float4 v4 = ld4(vl + c * 256 + p4);
        #pragma unroll
        for (int q = 0; q < 8; ++q) {
          float s = kwT[(d0 + q) * 33 + c];
          acc[q].x += v4.x * s; acc[q].y += v4.y * s;
          acc[q].z += v4.z * s; acc[q].w += v4.w * s;
        }
      }
      #pragma unroll
      for (int q = 0; q < 8; ++q)
        st4(wkvB + (size_t)(d0 + q) * 256 + p4, acc[q]);
    }
  }
  // phase 6: A[i][j] = sum_d qe2[i,d]*kv[j,d]; mask + diag
  {
    const int j = tid & 31, i2 = tid >> 5;  // i2 0..15 -> rows i2, i2+16
    float a0 = 0.f, a1 = 0.f;
    for (int d = 0; d < 128; ++d) {
      float kv = kwT[d * 33 + j];
      a0 += qeT[d * 33 + i2] * kv;
      a1 += qeT[d * 33 + i2 + 16] * kv;
    }
    Al[i2 * 33 + j] = (j < i2) ? a0 : ((j == i2) ? diag[i2] : 0.f);
    Al[(i2 + 16) * 33 + j] = (j < i2 + 16) ? a1 : ((j == i2 + 16) ? diag[i2 + 16] : 0.f);
  }
  __syncthreads();
  // phase 7: o_intra = A @ v
  {
    float4 acc[4];
    #pragma unroll
    for (int q = 0; q < 4; ++q) acc[q] = make_float4(0, 0, 0, 0);
    for (int c = 0; c < 32; ++c) {
      float4 v4 = ld4(vl + c * 256 + p4);
      #pragma unroll
      for (int q = 0; q < 4; ++q) {
        float a = Al[(wvx * 4 + q) * 33 + c];
        acc[q].x += v4.x * a; acc[q].y += v4.y * a;
        acc[q].z += v4.z * a; acc[q].w += v4.w * a;
      }
    }
    #pragma unroll
    for (int q = 0; q < 4; ++q)
      st4(oG + (size_t)(tb + wvx * 4 + q) * 1024 + h * 256 + p4, acc[q]);
  }
}

// ---------------------------------------------------------------- kernel D2
// inter-chunk scan, 2 waves per (b,h,d)-row (float2 lanes), 4-deep prefetch.
__global__ __launch_bounds__(256) void kD2(float* __restrict__ wkvG,
                                           const float* __restrict__ decayG) {
  const int wvid = (blockIdx.x * 256 + threadIdx.x) >> 6;  // 0..2047
  const int lane = threadIdx.x & 63;
  const int half = wvid & 1;
  const int d = (wvid >> 1) & 127;
  const int bh = wvid >> 8;
  const int p2 = half * 128 + lane * 2;
  float* base = wkvG + ((size_t)bh * 64 * 128 + d) * 256 + p2;
  const float* dbase = decayG + (size_t)bh * 64 * 128 + d;
  float2 kvb[4];
  float decb[4];
  #pragma unroll
  for (int i = 0; i < 4; ++i) {
    kvb[i] = ld2(base + (size_t)i * 32768);
    decb[i] = dbase[(size_t)i * 128];
  }
  float2 S = make_float2(0.f, 0.f);
  #pragma unroll
  for (int nc = 0; nc < 64; ++nc) {
    const int sl = nc & 3;
    float2 kv = kvb[sl];
    float dec = decb[sl];
    if (nc + 4 < 64) {
      kvb[sl] = ld2(base + (size_t)(nc + 4) * 32768);
      decb[sl] = dbase[(size_t)(nc + 4) * 128];
    }
    st2(base + (size_t)nc * 32768, S);
    S.x = S.x * dec + kv.x;
    S.y = S.y * dec + kv.y;
  }
}

// ---------------------------------------------------------------- kernel D3
// o += qe @ S_before per chunk (f32)
__global__ __launch_bounds__(256) void kD3(
    const float* __restrict__ qeG, const float* __restrict__ wkvG,
    float* __restrict__ oG) {
  __shared__ float qel[32 * 129];
  const int tid = threadIdx.x;
  const int bid = blockIdx.x;
  const int nc = bid & 63, h = (bid >> 6) & 3, b = bid >> 8;
  const int tb = b * Lc + nc * 32;
  for (int it = 0; it < 16; ++it) {
    int idx = it * 256 + tid;
    int c = idx >> 7, d = idx & 127;
    qel[c * 129 + d] = qeG[(size_t)(tb + c) * 512 + h * 128 + d];
  }
  __syncthreads();
  const int pid = tid & 63, wvx = tid >> 6;
  const int p4 = pid * 4;
  const float* Sb = wkvG + (size_t)bid * (128 * 256);
  float4 acc[8];
  #pragma unroll
  for (int q = 0; q < 8; ++q) acc[q] = make_float4(0, 0, 0, 0);
  for (int d = 0; d < 128; ++d) {
    float4 s4 = ld4(Sb + (size_t)d * 256 + p4);
    #pragma unroll
    for (int q = 0; q < 8; ++q) {
      float qv = qel[(wvx * 8 + q) * 129 + d];
      acc[q].x += s4.x * qv; acc[q].y += s4.y * qv;
      acc[q].z += s4.z * qv; acc[q].w += s4.w * qv;
    }
  }
  #pragma unroll
  for (int q = 0; q < 8; ++q) {
    float* op = oG + (size_t)(tb + wvx * 8 + q) * 1024 + h * 256 + p4;
    float4 cur = ld4(op);
    cur.x += acc[q].x; cur.y += acc[q].y; cur.z += acc[q].z; cur.w += acc[q].w;
    st4(op, cur);
  }
}

// ---------------------------------------------------------------- kernel E
__global__ __launch_bounds__(256) void kE(
    const float* __restrict__ oG, const u16* __restrict__ gG,
    const float* __restrict__ gn_w, const float* __restrict__ gn_b,
    u16* __restrict__ gate) {
  const int t = blockIdx.x;
  const int h = threadIdx.x >> 6, lane = threadIdx.x & 63;
  const int p4 = lane * 4;
  const int vd = h * 256 + p4;
  float4 v = ld4(oG + (size_t)t * 1024 + vd);
  float s = v.x + v.y + v.z + v.w;
  float ss = v.x * v.x + v.y * v.y + v.z * v.z + v.w * v.w;
  for (int m = 1; m < 64; m <<= 1) {
    s += __shfl_xor(s, m, 64);
    ss += __shfl_xor(ss, m, 64);
  }
  const float mean = s * (1.f / 256.f);
  const float var = ss * (1.f / 256.f) - mean * mean;
  const float rs = rsqrtf(var + 1e-5f);
  float4 gw = ld4(gn_w + vd), gb = ld4(gn_b + vd);
  float4 on;
  on.x = (v.x - mean) * rs * gw.x + gb.x;
  on.y = (v.y - mean) * rs * gw.y + gb.y;
  on.z = (v.z - mean) * rs * gw.z + gb.z;
  on.w = (v.w - mean) * rs * gw.w + gb.w;
  ushort4 g4 = *reinterpret_cast<const ushort4*>(gG + (size_t)t * 1024 + vd);
  float gx = bf2f(g4.x), gy = bf2f(g4.y), gz = bf2f(g4.z), gw_ = bf2f(g4.w);
  float4 sw;
  sw.x = gx / (1.f + __expf(-gx));
  sw.y = gy / (1.f + __expf(-gy));
  sw.z = gz / (1.f + __expf(-gz));
  sw.w = gw_ / (1.f + __expf(-gw_));
  ushort4 ob;
  ob.x = f2bf(on.x * sw.x); ob.y = f2bf(on.y * sw.y);
  ob.z = f2bf(on.z * sw.z); ob.w = f2bf(on.w * sw.w);
  *reinterpret_cast<ushort4*>(gate + (size_t)t * 1024 + vd) = ob;
}

// ---------------------------------------------------------------- kernel F
__global__ __launch_bounds__(256) void kF(
    const u16* __restrict__ gate, const u16* __restrict__ owb,
    float* __restrict__ out) {
  __shared__ __align__(16) u16 Abuf[128 * 64];
  __shared__ __align__(16) u16 Bbuf[128 * 64];
  const int mt = blockIdx.x, nt = blockIdx.y;
  const u16* A = gate + (size_t)mt * 128 * 1024;
  const u16* W = owb + (size_t)nt * 128 * 1024;
  float* C = out + (size_t)mt * 128 * 1024 + nt * 128;
  const int tid = threadIdx.x;
  const int lane = tid & 63;
  const int wv = tid >> 6;
  const int wr = wv >> 1, wc = wv & 1;
  const int srow = wv * 32;
  f32x4 acc[4][4];
  #pragma unroll
  for (int i = 0; i < 4; ++i)
    #pragma unroll
    for (int j = 0; j < 4; ++j) acc[i][j] = {0.f, 0.f, 0.f, 0.f};
  for (int k0 = 0; k0 < 1024; k0 += 64) {
    #pragma unroll
    for (int c = 0; c < 4; ++c) {
      const int r = srow + c * 8 + (lane >> 3);
      const int col = (lane & 7) * 8;
      __builtin_amdgcn_global_load_lds(
          (gu32*)(const void*)(A + (size_t)r * 1024 + k0 + col),
          (lu32*)(void*)(Abuf + (srow + c * 8) * 64), 16, 0, 0);
      __builtin_amdgcn_global_load_lds(
          (gu32*)(const void*)(W + (size_t)r * 1024 + k0 + col),
          (lu32*)(void*)(Bbuf + (srow + c * 8) * 64), 16, 0, 0);
    }
    __syncthreads();
    #pragma unroll
    for (int kk = 0; kk < 2; ++kk) {
      short8 af[4], bfr[4];
      #pragma unroll
      for (int m = 0; m < 4; ++m) {
        int row = wr * 64 + m * 16 + (lane & 15);
        af[m] = *reinterpret_cast<const short8*>(Abuf + row * 64 + kk * 32 + (lane >> 4) * 8);
      }
      #pragma unroll
      for (int j = 0; j < 4; ++j) {
        int row = wc * 64 + j * 16 + (lane & 15);
        bfr[j] = *reinterpret_cast<const short8*>(Bbuf + row * 64 + kk * 32 + (lane >> 4) * 8);
      }
      #pragma unroll
      for (int m = 0; m < 4; ++m)
        #pragma unroll
        for (int j = 0; j < 4; ++j)
          acc[m][j] = __builtin_amdgcn_mfma_f32_16x16x32_bf16(af[m], bfr[j], acc[m][j], 0, 0, 0);
    }
    __syncthreads();
  }
  #pragma unroll
  for (int m = 0; m < 4; ++m)
    #pragma unroll
    for (int r = 0; r < 4; ++r) {
      const int row = wr * 64 + m * 16 + (lane >> 4) * 4 + r;
      #pragma unroll
      for (int j = 0; j < 4; ++j) {
        const int col = wc * 64 + j * 16 + (lane & 15);
        C[(size_t)row * 1024 + col] = acc[m][j][r];
      }
    }
}

}  // namespace

extern "C" void kernel_launch(void* const* d_in, const int* in_sizes, int n_in,
                              void* d_out, int out_size, void* d_ws, size_t ws_size,
                              hipStream_t stream) {
  (void)in_sizes; (void)n_in; (void)out_size;
  if (ws_size < WS_NEED) return;

  const float* x      = (const float*)d_in[0];
  const float* x0_mu  = (const float*)d_in[1];
  const float* x0_w   = (const float*)d_in[2];
  const float* x2_w   = (const float*)d_in[3];
  const float* x_bias = (const float*)d_in[4];
  const float* r_w    = (const float*)d_in[5];
  const float* w_w1   = (const float*)d_in[6];
  const float* w_w2   = (const float*)d_in[7];
  const float* w_b2   = (const float*)d_in[8];
  const float* k_w    = (const float*)d_in[9];
  const float* v_w    = (const float*)d_in[10];
  const float* g_w    = (const float*)d_in[11];
  const float* bonus  = (const float*)d_in[12];
  const float* gn_w   = (const float*)d_in[13];
  const float* gn_b   = (const float*)d_in[14];
  const float* o_w    = (const float*)d_in[15];
  float* out = (float*)d_out;
  char* ws = (char*)d_ws;

  float* wkvG   = (float*)(ws + OFF_WKV);
  float* xm0    = (float*)(ws + OFF_XM0);
  float* delta  = (float*)(ws + OFF_DELTA);
  float* t160   = (float*)(ws + OFF_T160);
  float* xmw    = (float*)(ws + OFF_XMW);
  float* yw     = (float*)(ws + OFF_YW);
  u16*   xmhi   = (u16*)(ws + OFF_XMHI);
  float* wfin   = (float*)(ws + OFF_WFIN);
  u16*   gate   = (u16*)(ws + OFF_GATE);
  u16*   xmlo   = (u16*)(ws + OFF_XMLO);
  float* qeG    = (float*)(ws + OFF_QE);
  float* oG     = (float*)(ws + OFF_OO);
  u16*   Whi    = (u16*)(ws + OFF_WHI);
  u16*   Wlo    = (u16*)(ws + OFF_WLO);
  float* decayG = (float*)(ws + OFF_DECAY);
  u16*   owb    = (u16*)(ws + OFF_OWB);
  float* rG     = (float*)(ws + OFF_RG);
  float* kG     = (float*)(ws + OFF_KG);
  float* vG     = (float*)(ws + OFF_VG);
  u16*   gG     = (u16*)(ws + OFF_GG);

  const size_t ldsD1 = (size_t)(8192 + 4224 + 4224 + 1056 + 32) * 4;  // 70,912 B

  kW   <<<dim3(4096),      dim3(256), 0, stream>>>(r_w, k_w, v_w, g_w, o_w, Whi, Wlo, owb);
  kA1  <<<dim3(4096),      dim3(256), 0, stream>>>(x, x0_mu, xm0, delta);
  kA2  <<<dim3(32, 5),     dim3(256), 0, stream>>>(xm0, x0_w, t160);
  kA2mf<<<dim3(64, 16),    dim3(256), 0, stream>>>(t160, x2_w, x_bias, xm0, delta,
                                                   x0_mu, xmhi, xmlo, xmw);
  kWL  <<<dim3(128),       dim3(256), 0, stream>>>(xmw, w_w1, yw);
  kB   <<<dim3(32, 24),    dim3(256), 0, stream>>>(xmhi, xmlo, Whi, Wlo, rG, kG, vG, gG);
  kC   <<<dim3(128, 2),    dim3(256), 0, stream>>>(yw, w_w2, w_b2, wfin);
  kD1  <<<dim3(512),       dim3(512), ldsD1, stream>>>(rG, kG, vG, wfin, bonus,
                                                       wkvG, decayG, qeG, oG);
  kD2  <<<dim3(512),       dim3(256), 0, stream>>>(wkvG, decayG);
  kD3  <<<dim3(512),       dim3(256), 0, stream>>>(qeG, wkvG, oG);
  kE   <<<dim3(4096),      dim3(256), 0, stream>>>(oG, gG, gn_w, gn_b, gate);
  kF   <<<dim3(32, 8),     dim3(256), 0, stream>>>(gate, owb, out);
}

// Round 6
// 407.186 us; speedup vs baseline: 3.1851x; 1.0910x over previous
//
#include <hip/hip_runtime.h>

// RWKV6Attention forward — round 6: XOR-swizzled MFMA staging (kB/kF/kA2f),
// per-plane fused mix kernel (kA2m5), t160 GEMM moved to MFMA bf16x3 (kA2f).

#define DEVI __device__ __forceinline__

namespace {

typedef unsigned short u16;
typedef unsigned int u32;
typedef __attribute__((ext_vector_type(8))) short short8;   // 8 bf16 (4 VGPRs)
typedef __attribute__((ext_vector_type(4))) float f32x4;

typedef __attribute__((address_space(1))) const u32 gu32;
typedef __attribute__((address_space(3))) u32 lu32;

constexpr int Lc = 2048;
constexpr int Tc = 4096;   // B*L

// ---- workspace layout (byte offsets), lifetime-safe aliasing.
constexpr size_t OFF_WKV   = 0;            // f32 [512][128][256] (kD1+)
constexpr size_t OFF_XM0   = 0;            // f32 [T][1024]  dead after kA2m5
constexpr size_t OFF_DELTA = 16777216;     // f32 [T][1024]  dead after kA2m5
constexpr size_t OFF_T160  = 33554432;     // f32 [T][160]   dead after kA2m5
constexpr size_t OFF_XMW   = 36175872;     // f32 [T][1024]  dead after kWL
constexpr size_t OFF_YW    = 52953088;     // f32 [T][64]    dead after kC
constexpr size_t OFF_X0WHI = 54001664;     // bf16 [160][1024] dead after kA2f
constexpr size_t OFF_X0WLO = 54329344;     // bf16 [160][1024] dead after kA2f
constexpr size_t OFF_XMHI  = 67108864;     // bf16 [4][T][1024] (kA2m5 -> kB)
constexpr size_t OFF_XM0HI = 67108864;     //   bf16 [T][1024] (kA1 -> kA2f, dead < kA2m5)
constexpr size_t OFF_XM0LO = 75497472;     //   bf16 [T][1024] (kA1 -> kA2f)
constexpr size_t OFF_WFIN  = 67108864;     //   f32 [T][512]  (kC -> kD1, after kB)
constexpr size_t OFF_GATE  = 75497472;     //   bf16 [T][1024] (kE -> kF)
constexpr size_t OFF_XMLO  = 100663296;    // bf16 [3][T][1024] dead after kB
constexpr size_t OFF_QE    = 100663296;    //   f32 [T][512]   (kD1 -> kD3)
constexpr size_t OFF_OO    = 109051904;    //   f32 [T][1024]  (kD1 -> kE)
constexpr size_t OFF_WHI   = 125829120;    // bf16 [3072][1024] dead after kB
constexpr size_t OFF_WLO   = 132120576;    // bf16 [2048][1024] dead after kB
constexpr size_t OFF_DECAY = 132120576;    //   f32 [512][128]  (kD1 -> kD2)
constexpr size_t OFF_OWB   = 136314880;    // bf16 [1024][1024] (kW -> kF)
constexpr size_t OFF_RG    = 138412032;    // f32 [T][512]
constexpr size_t OFF_KG    = 146800640;    // f32 [T][512]
constexpr size_t OFF_VG    = 155189248;    // f32 [T][1024]
constexpr size_t OFF_GG    = 171966464;    // bf16 [T][1024]
constexpr size_t WS_NEED   = 180355072;

DEVI float4 ld4(const float* p) { return *reinterpret_cast<const float4*>(p); }
DEVI void   st4(float* p, float4 v) { *reinterpret_cast<float4*>(p) = v; }
DEVI float2 ld2(const float* p) { return *reinterpret_cast<const float2*>(p); }
DEVI void   st2(float* p, float2 v) { *reinterpret_cast<float2*>(p) = v; }
DEVI u16 f2bf(float f) {
  u32 u = __float_as_uint(f);
  return (u16)((u + 0x7FFFu + ((u >> 16) & 1u)) >> 16);
}
DEVI float bf2f(u16 u) { return __uint_as_float((u32)u << 16); }

// stage one 8-row chunk (1 KB) of a [128][64]-u16 tile with source-side XOR
// swizzle; LDS dest stays linear (rule: swizzle source + read, never dest).
DEVI void stage_swz(const u16* __restrict__ src, u16* __restrict__ dstBase,
                    int srow8, int k0, int lane) {
  const int rr = srow8 + (lane >> 3);
  const int ss = (lane & 7) ^ ((lane >> 3) & 7);
  __builtin_amdgcn_global_load_lds(
      (gu32*)(const void*)(src + (size_t)rr * 1024 + k0 + ss * 8),
      (lu32*)(void*)(dstBase + srow8 * 64), 16, 0, 0);
}
// swizzled read: slot_lin in 0..7, row in 0..127
DEVI short8 read_swz(const u16* __restrict__ buf, int row, int slot_lin) {
  return *reinterpret_cast<const short8*>(buf + row * 64 + ((slot_lin ^ (row & 7)) * 8));
}

// ---------------------------------------------------------------- kernel W
// proj weights -> Whi (+ Wlo for r,k,v), o_w -> owb, x0_w -> hi/lo bf16.
__global__ void kW(const float* __restrict__ r_w, const float* __restrict__ k_w,
                   const float* __restrict__ v_w, const float* __restrict__ g_w,
                   const float* __restrict__ o_w, const float* __restrict__ x0_w,
                   u16* __restrict__ Whi, u16* __restrict__ Wlo,
                   u16* __restrict__ owb, u16* __restrict__ x0whi,
                   u16* __restrict__ x0wlo) {
  const size_t i = ((size_t)blockIdx.x * 256 + threadIdx.x) * 4;
  if (i < 3145728) {
    const float* src = (i < 524288)  ? r_w + i
                     : (i < 1048576) ? k_w + (i - 524288)
                     : (i < 2097152) ? v_w + (i - 1048576)
                                     : g_w + (i - 2097152);
    float4 v = ld4(src);
    ushort4 h;
    h.x = f2bf(v.x); h.y = f2bf(v.y); h.z = f2bf(v.z); h.w = f2bf(v.w);
    *reinterpret_cast<ushort4*>(Whi + i) = h;
    if (i < 2097152) {
      ushort4 l;
      l.x = f2bf(v.x - bf2f(h.x)); l.y = f2bf(v.y - bf2f(h.y));
      l.z = f2bf(v.z - bf2f(h.z)); l.w = f2bf(v.w - bf2f(h.w));
      *reinterpret_cast<ushort4*>(Wlo + i) = l;
    }
  } else if (i < 4194304) {
    float4 v = ld4(o_w + (i - 3145728));
    ushort4 h;
    h.x = f2bf(v.x); h.y = f2bf(v.y); h.z = f2bf(v.z); h.w = f2bf(v.w);
    *reinterpret_cast<ushort4*>(owb + (i - 3145728)) = h;
  } else {
    const size_t j = i - 4194304;     // x0_w: 163,840 elems
    float4 v = ld4(x0_w + j);
    ushort4 h, l;
    h.x = f2bf(v.x); h.y = f2bf(v.y); h.z = f2bf(v.z); h.w = f2bf(v.w);
    l.x = f2bf(v.x - bf2f(h.x)); l.y = f2bf(v.y - bf2f(h.y));
    l.z = f2bf(v.z - bf2f(h.z)); l.w = f2bf(v.w - bf2f(h.w));
    *reinterpret_cast<ushort4*>(x0whi + j) = h;
    *reinterpret_cast<ushort4*>(x0wlo + j) = l;
  }
}

// ---------------------------------------------------------------- kernel A1
// delta, xm0 (f32) + xm0 hi/lo bf16 planes for the t160 MFMA GEMM.
__global__ void kA1(const float* __restrict__ x, const float* __restrict__ x0_mu,
                    float* __restrict__ xm0, float* __restrict__ delta,
                    u16* __restrict__ xm0hi, u16* __restrict__ xm0lo) {
  const size_t i4 = (size_t)blockIdx.x * 256 + threadIdx.x;
  const int t = (int)(i4 >> 8);
  const int h4 = (int)(i4 & 255) * 4;
  float4 xv = ld4(x + (size_t)t * 1024 + h4);
  float4 xp = make_float4(0.f, 0.f, 0.f, 0.f);
  if (t & (Lc - 1)) xp = ld4(x + (size_t)(t - 1) * 1024 + h4);
  float4 mu = ld4(x0_mu + h4);
  float4 d;
  d.x = xp.x - xv.x; d.y = xp.y - xv.y; d.z = xp.z - xv.z; d.w = xp.w - xv.w;
  st4(delta + (size_t)t * 1024 + h4, d);
  float4 m0;
  m0.x = xv.x + d.x * mu.x; m0.y = xv.y + d.y * mu.y;
  m0.z = xv.z + d.z * mu.z; m0.w = xv.w + d.w * mu.w;
  st4(xm0 + (size_t)t * 1024 + h4, m0);
  ushort4 h, l;
  h.x = f2bf(m0.x); h.y = f2bf(m0.y); h.z = f2bf(m0.z); h.w = f2bf(m0.w);
  l.x = f2bf(m0.x - bf2f(h.x)); l.y = f2bf(m0.y - bf2f(h.y));
  l.z = f2bf(m0.z - bf2f(h.z)); l.w = f2bf(m0.w - bf2f(h.w));
  *reinterpret_cast<ushort4*>(xm0hi + (size_t)t * 1024 + h4) = h;
  *reinterpret_cast<ushort4*>(xm0lo + (size_t)t * 1024 + h4) = l;
}

// ---------------------------------------------------------------- kernel A2f
// t160[T][160] = tanh(xm0 @ x0_w^T) via bf16x3 MFMA. nt=0: cols 0..127;
// nt=1: cols 128..159 (B rows wrapped, stores guarded).
__global__ __launch_bounds__(256) void kA2f(
    const u16* __restrict__ xm0hi, const u16* __restrict__ xm0lo,
    const u16* __restrict__ x0whi, const u16* __restrict__ x0wlo,
    float* __restrict__ t160) {
  __shared__ __align__(16) u16 sAh[128 * 64];
  __shared__ __align__(16) u16 sAl[128 * 64];
  __shared__ __align__(16) u16 sBh[128 * 64];
  __shared__ __align__(16) u16 sBl[128 * 64];
  const int mt = blockIdx.x, nt = blockIdx.y;
  const int ncols = nt ? 32 : 128;
  const int wcol0 = nt * 128;
  const u16* Ah = xm0hi + (size_t)mt * 128 * 1024;
  const u16* Al = xm0lo + (size_t)mt * 128 * 1024;
  const u16* Bh = x0whi + (size_t)wcol0 * 1024;
  const u16* Bl = x0wlo + (size_t)wcol0 * 1024;
  const int tid = threadIdx.x;
  const int lane = tid & 63;
  const int wv = tid >> 6;
  const int wr = wv >> 1, wc = wv & 1;
  const int srow = wv * 32;
  f32x4 acc[4][4];
  #pragma unroll
  for (int i = 0; i < 4; ++i)
    #pragma unroll
    for (int j = 0; j < 4; ++j) acc[i][j] = {0.f, 0.f, 0.f, 0.f};

  for (int k0 = 0; k0 < 1024; k0 += 64) {
    #pragma unroll
    for (int c = 0; c < 4; ++c) {
      const int s8 = srow + c * 8;
      stage_swz(Ah, sAh, s8, k0, lane);
      stage_swz(Al, sAl, s8, k0, lane);
      // B rows wrapped into valid range (garbage rows unused)
      {
        const int rr = (s8 + (lane >> 3)) & (ncols - 1);
        const int ss = (lane & 7) ^ ((lane >> 3) & 7);
        __builtin_amdgcn_global_load_lds(
            (gu32*)(const void*)(Bh + (size_t)rr * 1024 + k0 + ss * 8),
            (lu32*)(void*)(sBh + s8 * 64), 16, 0, 0);
        __builtin_amdgcn_global_load_lds(
            (gu32*)(const void*)(Bl + (size_t)rr * 1024 + k0 + ss * 8),
            (lu32*)(void*)(sBl + s8 * 64), 16, 0, 0);
      }
    }
    __syncthreads();
    #pragma unroll
    for (int kk = 0; kk < 2; ++kk) {
      const int sl = kk * 4 + (lane >> 4);
      short8 ah[4], al[4], bh[4], bl[4];
      #pragma unroll
      for (int m = 0; m < 4; ++m) {
        int row = wr * 64 + m * 16 + (lane & 15);
        ah[m] = read_swz(sAh, row, sl);
        al[m] = read_swz(sAl, row, sl);
      }
      #pragma unroll
      for (int j = 0; j < 4; ++j) {
        int row = wc * 64 + j * 16 + (lane & 15);
        bh[j] = read_swz(sBh, row, sl);
        bl[j] = read_swz(sBl, row, sl);
      }
      #pragma unroll
      for (int m = 0; m < 4; ++m)
        #pragma unroll
        for (int j = 0; j < 4; ++j) {
          acc[m][j] = __builtin_amdgcn_mfma_f32_16x16x32_bf16(ah[m], bh[j], acc[m][j], 0, 0, 0);
          acc[m][j] = __builtin_amdgcn_mfma_f32_16x16x32_bf16(al[m], bh[j], acc[m][j], 0, 0, 0);
          acc[m][j] = __builtin_amdgcn_mfma_f32_16x16x32_bf16(ah[m], bl[j], acc[m][j], 0, 0, 0);
        }
    }
    __syncthreads();
  }
  #pragma unroll
  for (int m = 0; m < 4; ++m)
    #pragma unroll
    for (int r = 0; r < 4; ++r) {
      const int row = wr * 64 + m * 16 + (lane >> 4) * 4 + r;
      #pragma unroll
      for (int j = 0; j < 4; ++j) {
        const int col = wc * 64 + j * 16 + (lane & 15);
        if (col < ncols)
          t160[(size_t)(mt * 128 + row) * 160 + wcol0 + col] = tanhf(acc[m][j][r]);
      }
    }
}

// ---------------------------------------------------------------- kernel A2m5
// one plane per blockIdx.z: mix = t160slice @ x2_wslice^T + bias;
// plane = xm0 + delta*(mix - mu) -> hi/lo bf16 (r,k,v), hi (g), f32 (w).
__global__ __launch_bounds__(256) void kA2m5(
    const float* __restrict__ t160G, const float* __restrict__ x2_w,
    const float* __restrict__ x_bias, const float* __restrict__ xm0,
    const float* __restrict__ delta, const float* __restrict__ x0_mu,
    u16* __restrict__ xmhi, u16* __restrict__ xmlo, float* __restrict__ xmw) {
  __shared__ float As[64 * 33];
  __shared__ float Ws[64 * 33];
  const int tid = threadIdx.x;
  const int m0 = blockIdx.x * 64, h0 = blockIdx.y * 64, n = blockIdx.z;
  #pragma unroll
  for (int c = 0; c < 2; ++c) {
    int r = c * 32 + (tid >> 3);
    int col = (tid & 7) * 4;
    float4 a4 = ld4(t160G + (size_t)(m0 + r) * 160 + n * 32 + col);
    As[r * 33 + col + 0] = a4.x; As[r * 33 + col + 1] = a4.y;
    As[r * 33 + col + 2] = a4.z; As[r * 33 + col + 3] = a4.w;
    float4 w4 = ld4(x2_w + (size_t)(h0 + r) * 160 + n * 32 + col);
    Ws[r * 33 + col + 0] = w4.x; Ws[r * 33 + col + 1] = w4.y;
    Ws[r * 33 + col + 2] = w4.z; Ws[r * 33 + col + 3] = w4.w;
  }
  __syncthreads();
  const int rm = (tid >> 4) * 4, cn = (tid & 15) * 4;
  float acc[4][4] = {};
  #pragma unroll
  for (int kk = 0; kk < 32; ++kk) {
    float a[4], w[4];
    #pragma unroll
    for (int i = 0; i < 4; ++i) a[i] = As[(rm + i) * 33 + kk];
    #pragma unroll
    for (int j = 0; j < 4; ++j) w[j] = Ws[(cn + j) * 33 + kk];
    #pragma unroll
    for (int i = 0; i < 4; ++i)
      #pragma unroll
      for (int j = 0; j < 4; ++j) acc[i][j] += a[i] * w[j];
  }
  const float4 b4 = ld4(x_bias + n * 1024 + h0 + cn);
  const float4 mu4 = ld4(x0_mu + h0 + cn);
  const int pi = (n == 0) ? 0 : (n == 2) ? 1 : (n == 3) ? 2 : 3;
  #pragma unroll
  for (int i = 0; i < 4; ++i) {
    const size_t rowo = (size_t)(m0 + rm + i) * 1024 + h0 + cn;
    float4 xm4 = ld4(xm0 + rowo);
    float4 dv4 = ld4(delta + rowo);
    float4 o;
    o.x = xm4.x + dv4.x * (acc[i][0] + b4.x - mu4.x);
    o.y = xm4.y + dv4.y * (acc[i][1] + b4.y - mu4.y);
    o.z = xm4.z + dv4.z * (acc[i][2] + b4.z - mu4.z);
    o.w = xm4.w + dv4.w * (acc[i][3] + b4.w - mu4.w);
    if (n == 1) {
      st4(xmw + rowo, o);
    } else {
      ushort4 h;
      h.x = f2bf(o.x); h.y = f2bf(o.y); h.z = f2bf(o.z); h.w = f2bf(o.w);
      *reinterpret_cast<ushort4*>(xmhi + (size_t)pi * Tc * 1024 + rowo) = h;
      if (n != 4) {
        ushort4 l;
        l.x = f2bf(o.x - bf2f(h.x)); l.y = f2bf(o.y - bf2f(h.y));
        l.z = f2bf(o.z - bf2f(h.z)); l.w = f2bf(o.w - bf2f(h.w));
        *reinterpret_cast<ushort4*>(xmlo + (size_t)pi * Tc * 1024 + rowo) = l;
      }
    }
  }
}

// ---------------------------------------------------------------- kernel WL
// y_w[T][64] = tanh(xmw @ w_w1^T), fp32
__global__ __launch_bounds__(256) void kWL(
    const float* __restrict__ xmw, const float* __restrict__ w_w1,
    float* __restrict__ yw) {
  __shared__ float As[32 * 33];
  __shared__ float Ws[64 * 33];
  const int tid = threadIdx.x;
  const int t0 = blockIdx.x * 32;
  const int rg = tid >> 5;
  const int cg = tid & 31;
  float acc[4][2] = {};
  for (int k0 = 0; k0 < 1024; k0 += 32) {
    __syncthreads();
    {
      int r = tid >> 3, c4 = (tid & 7) * 4;
      float4 a4 = ld4(xmw + (size_t)(t0 + r) * 1024 + k0 + c4);
      As[r * 33 + c4 + 0] = a4.x; As[r * 33 + c4 + 1] = a4.y;
      As[r * 33 + c4 + 2] = a4.z; As[r * 33 + c4 + 3] = a4.w;
    }
    #pragma unroll
    for (int c = 0; c < 2; ++c) {
      int r = c * 32 + (tid >> 3), c4 = (tid & 7) * 4;
      float4 w4 = ld4(w_w1 + (size_t)r * 1024 + k0 + c4);
      Ws[r * 33 + c4 + 0] = w4.x; Ws[r * 33 + c4 + 1] = w4.y;
      Ws[r * 33 + c4 + 2] = w4.z; Ws[r * 33 + c4 + 3] = w4.w;
    }
    __syncthreads();
    #pragma unroll
    for (int kk = 0; kk < 32; ++kk) {
      float a[4];
      #pragma unroll
      for (int i = 0; i < 4; ++i) a[i] = As[(rg * 4 + i) * 33 + kk];
      float w0 = Ws[cg * 33 + kk], w1 = Ws[(cg + 32) * 33 + kk];
      #pragma unroll
      for (int i = 0; i < 4; ++i) { acc[i][0] += a[i] * w0; acc[i][1] += a[i] * w1; }
    }
  }
  #pragma unroll
  for (int i = 0; i < 4; ++i) {
    yw[(size_t)(t0 + rg * 4 + i) * 64 + cg]      = tanhf(acc[i][0]);
    yw[(size_t)(t0 + rg * 4 + i) * 64 + cg + 32] = tanhf(acc[i][1]);
  }
}

// -------------------------------------------- bf16x3 MFMA GEMM, pre-split A
__global__ __launch_bounds__(256) void kB(
    const u16* __restrict__ xmhi, const u16* __restrict__ xmlo,
    const u16* __restrict__ Whi, const u16* __restrict__ Wlo,
    float* __restrict__ rG, float* __restrict__ kG,
    float* __restrict__ vG, u16* __restrict__ gG) {
  __shared__ __align__(16) u16 sAh[128 * 64];
  __shared__ __align__(16) u16 sAl[128 * 64];
  __shared__ __align__(16) u16 sBh[128 * 64];
  __shared__ __align__(16) u16 sBl[128 * 64];
  const int mt = blockIdx.x, nt = blockIdx.y;
  int plane, col0, ldc;
  float* Cf = nullptr;
  u16* Cb = nullptr;
  bool three = true;
  if (nt < 4)       { plane = 0; Cf = rG; ldc = 512;  col0 = nt * 128; }
  else if (nt < 8)  { plane = 1; Cf = kG; ldc = 512;  col0 = (nt - 4) * 128; }
  else if (nt < 16) { plane = 2; Cf = vG; ldc = 1024; col0 = (nt - 8) * 128; }
  else              { plane = 3; Cb = gG; ldc = 1024; col0 = (nt - 16) * 128; three = false; }
  const u16* Ah = xmhi + ((size_t)plane * Tc + (size_t)mt * 128) * 1024;
  const u16* Al = xmlo + ((size_t)plane * Tc + (size_t)mt * 128) * 1024;
  const u16* Bh = Whi + (size_t)nt * 128 * 1024;
  const u16* Bl = Wlo + (size_t)nt * 128 * 1024;

  const int tid = threadIdx.x;
  const int lane = tid & 63;
  const int wv = tid >> 6;
  const int wr = wv >> 1, wc = wv & 1;
  const int srow = wv * 32;
  f32x4 acc[4][4];
  #pragma unroll
  for (int i = 0; i < 4; ++i)
    #pragma unroll
    for (int j = 0; j < 4; ++j) acc[i][j] = {0.f, 0.f, 0.f, 0.f};

  for (int k0 = 0; k0 < 1024; k0 += 64) {
    #pragma unroll
    for (int c = 0; c < 4; ++c) {
      const int s8 = srow + c * 8;
      stage_swz(Ah, sAh, s8, k0, lane);
      stage_swz(Bh, sBh, s8, k0, lane);
      if (three) {
        stage_swz(Al, sAl, s8, k0, lane);
        stage_swz(Bl, sBl, s8, k0, lane);
      }
    }
    __syncthreads();
    #pragma unroll
    for (int kk = 0; kk < 2; ++kk) {
      const int sl = kk * 4 + (lane >> 4);
      short8 ah[4], al[4], bh[4], bl[4];
      #pragma unroll
      for (int m = 0; m < 4; ++m) {
        int row = wr * 64 + m * 16 + (lane & 15);
        ah[m] = read_swz(sAh, row, sl);
        if (three) al[m] = read_swz(sAl, row, sl);
      }
      #pragma unroll
      for (int j = 0; j < 4; ++j) {
        int row = wc * 64 + j * 16 + (lane & 15);
        bh[j] = read_swz(sBh, row, sl);
        if (three) bl[j] = read_swz(sBl, row, sl);
      }
      #pragma unroll
      for (int m = 0; m < 4; ++m)
        #pragma unroll
        for (int j = 0; j < 4; ++j) {
          acc[m][j] = __builtin_amdgcn_mfma_f32_16x16x32_bf16(ah[m], bh[j], acc[m][j], 0, 0, 0);
          if (three) {
            acc[m][j] = __builtin_amdgcn_mfma_f32_16x16x32_bf16(al[m], bh[j], acc[m][j], 0, 0, 0);
            acc[m][j] = __builtin_amdgcn_mfma_f32_16x16x32_bf16(ah[m], bl[j], acc[m][j], 0, 0, 0);
          }
        }
    }
    __syncthreads();
  }
  #pragma unroll
  for (int m = 0; m < 4; ++m)
    #pragma unroll
    for (int r = 0; r < 4; ++r) {
      const int row = wr * 64 + m * 16 + (lane >> 4) * 4 + r;
      #pragma unroll
      for (int j = 0; j < 4; ++j) {
        const int col = wc * 64 + j * 16 + (lane & 15);
        float v = acc[m][j][r];
        if (Cf) Cf[(size_t)(mt * 128 + row) * ldc + col0 + col] = v;
        else    Cb[(size_t)(mt * 128 + row) * ldc + col0 + col] = f2bf(v);
      }
    }
}

// ---------------------------------------------------------------- kernel C
__global__ __launch_bounds__(256) void kC(
    const float* __restrict__ yw, const float* __restrict__ w_w2,
    const float* __restrict__ w_b2, float* __restrict__ wfin) {
  __shared__ float th[32 * 68];
  const int tid = threadIdx.x;
  const int t0 = blockIdx.x * 32;
  for (int idx = tid; idx < 32 * 64; idx += 256) {
    int i = idx >> 6, j = idx & 63;
    th[i * 68 + j] = yw[(size_t)(t0 + i) * 64 + j];
  }
  __syncthreads();
  const int c = blockIdx.y * 256 + tid;
  float acc[32] = {};
  const float* w2 = w_w2 + (size_t)c * 64;
  for (int k = 0; k < 64; k += 4) {
    float4 wv = ld4(w2 + k);
    #pragma unroll
    for (int i = 0; i < 32; ++i) {
      float4 t4 = ld4(th + i * 68 + k);
      acc[i] += t4.x * wv.x + t4.y * wv.y + t4.z * wv.z + t4.w * wv.w;
    }
  }
  const float b = w_b2[c];
  #pragma unroll
  for (int i = 0; i < 32; ++i)
    wfin[(size_t)(t0 + i) * 512 + c] = -__expf(acc[i] + b);
}

// ---------------------------------------------------------------- kernel D1
__global__ __launch_bounds__(512) void kD1(
    const float* __restrict__ rG, const float* __restrict__ kG,
    const float* __restrict__ vG, const float* __restrict__ wfin,
    const float* __restrict__ bonus, float* __restrict__ wkvG,
    float* __restrict__ decayG, float* __restrict__ qeG, float* __restrict__ oG) {
  extern __shared__ float sm[];
  float* vl   = sm;                 // [32][256]
  float* wcl  = sm;                 // [32][129] alias (dead before vl load)
  float* kwT  = sm + 8192;          // [128][33]
  float* qeT  = kwT + 4224;         // [128][33]
  float* Al   = qeT + 4224;         // [32][33]
  float* diag = Al + 1056;          // [32]
  const int tid = threadIdx.x;
  const int bid = blockIdx.x;
  const int nc = bid & 63, h = (bid >> 6) & 3, b = bid >> 8;
  const int tb = b * Lc + nc * 32;

  #pragma unroll
  for (int it = 0; it < 2; ++it) {
    int idx = it * 512 + tid;
    int c = idx >> 5, d4 = (idx & 31) * 4;
    float4 w4 = ld4(wfin + (size_t)(tb + c) * 512 + h * 128 + d4);
    wcl[c * 129 + d4 + 0] = w4.x; wcl[c * 129 + d4 + 1] = w4.y;
    wcl[c * 129 + d4 + 2] = w4.z; wcl[c * 129 + d4 + 3] = w4.w;
  }
  __syncthreads();
  if (tid < 128) {
    const int d = tid;
    float wv_[32];
    #pragma unroll
    for (int c = 0; c < 32; ++c) wv_[c] = wcl[c * 129 + d];
    float run = 0.f;
    #pragma unroll
    for (int c = 0; c < 32; ++c) { run += wv_[c]; wcl[c * 129 + d] = run; }
  } else if (tid < 160) {
    const int i = tid - 128;
    const float* qrow = rG + (size_t)(tb + i) * 512 + h * 128;
    const float* krow = kG + (size_t)(tb + i) * 512 + h * 128;
    const float* u = bonus + h * 128;
    float s0 = 0, s1 = 0, s2 = 0, s3 = 0;
    for (int d = 0; d < 128; d += 4) {
      s0 += qrow[d + 0] * u[d + 0] * krow[d + 0];
      s1 += qrow[d + 1] * u[d + 1] * krow[d + 1];
      s2 += qrow[d + 2] * u[d + 2] * krow[d + 2];
      s3 += qrow[d + 3] * u[d + 3] * krow[d + 3];
    }
    diag[i] = (s0 + s1) + (s2 + s3);
  }
  __syncthreads();
  #pragma unroll
  for (int it = 0; it < 8; ++it) {
    int idx = it * 512 + tid;
    int c = idx >> 7, d = idx & 127;
    int t = tb + c;
    float q = rG[(size_t)t * 512 + h * 128 + d];
    float k = kG[(size_t)t * 512 + h * 128 + d];
    float wcc = wcl[c * 129 + d];
    float wcp = (c > 0) ? wcl[(c - 1) * 129 + d] : 0.f;
    float wlast = wcl[31 * 129 + d];
    float qe = q * __expf(wcp);
    qeT[d * 33 + c] = q * __expf(wcp - wlast);
    kwT[d * 33 + c] = k * __expf(wlast - wcc);
    qeG[(size_t)t * 512 + h * 128 + d] = qe;
    if (c == 31) decayG[(size_t)bid * 128 + d] = __expf(wlast);
  }
  __syncthreads();
  #pragma unroll
  for (int it = 0; it < 4; ++it) {
    int idx = it * 512 + tid;
    int c = idx >> 6, p4 = (idx & 63) * 4;
    st4(vl + c * 256 + p4, ld4(vG + (size_t)(tb + c) * 1024 + h * 256 + p4));
  }
  __syncthreads();
  const int pid = tid & 63, wvx = tid >> 6;
  const int p4 = pid * 4;
  {
    float* wkvB = wkvG + (size_t)bid * (128 * 256);
    #pragma unroll
    for (int pp = 0; pp < 2; ++pp) {
      const int d0 = pp * 64 + wvx * 8;
      float4 acc[8];
      #pragma unroll
      for (int q = 0; q < 8; ++q) acc[q] = make_float4(0, 0, 0, 0);
      for (int c = 0; c < 32; ++c) {
        float4 v4 = ld4(vl + c * 256 + p4);
        #pragma unroll
        for (int q = 0; q < 8; ++q) {
          float s = kwT[(d0 + q) * 33 + c];
          acc[q].x += v4.x * s; acc[q].y += v4.y * s;
          acc[q].z += v4.z * s; acc[q].w += v4.w * s;
        }
      }
      #pragma unroll
      for (int q = 0; q < 8; ++q)
        st4(wkvB + (size_t)(d0 + q) * 256 + p4, acc[q]);
    }
  }
  {
    const int j = tid & 31, i2 = tid >> 5;
    float a0 = 0.f, a1 = 0.f;
    for (int d = 0; d < 128; ++d) {
      float kv = kwT[d * 33 + j];
      a0 += qeT[d * 33 + i2] * kv;
      a1 += qeT[d * 33 + i2 + 16] * kv;
    }
    Al[i2 * 33 + j] = (j < i2) ? a0 : ((j == i2) ? diag[i2] : 0.f);
    Al[(i2 + 16) * 33 + j] = (j < i2 + 16) ? a1 : ((j == i2 + 16) ? diag[i2 + 16] : 0.f);
  }
  __syncthreads();
  {
    float4 acc[4];
    #pragma unroll
    for (int q = 0; q < 4; ++q) acc[q] = make_float4(0, 0, 0, 0);
    for (int c = 0; c < 32; ++c) {
      float4 v4 = ld4(vl + c * 256 + p4);
      #pragma unroll
      for (int q = 0; q < 4; ++q) {
        float a = Al[(wvx * 4 + q) * 33 + c];
        acc[q].x += v4.x * a; acc[q].y += v4.y * a;
        acc[q].z += v4.z * a; acc[q].w += v4.w * a;
      }
    }
    #pragma unroll
    for (int q = 0; q < 4; ++q)
      st4(oG + (size_t)(tb + wvx * 4 + q) * 1024 + h * 256 + p4, acc[q]);
  }
}

// ---------------------------------------------------------------- kernel D2
__global__ __launch_bounds__(256) void kD2(float* __restrict__ wkvG,
                                           const float* __restrict__ decayG) {
  const int wvid = (blockIdx.x * 256 + threadIdx.x) >> 6;  // 0..2047
  const int lane = threadIdx.x & 63;
  const int half = wvid & 1;
  const int d = (wvid >> 1) & 127;
  const int bh = wvid >> 8;
  const int p2 = half * 128 + lane * 2;
  float* base = wkvG + ((size_t)bh * 64 * 128 + d) * 256 + p2;
  const float* dbase = decayG + (size_t)bh * 64 * 128 + d;
  float2 kvb[4];
  float decb[4];
  #pragma unroll
  for (int i = 0; i < 4; ++i) {
    kvb[i] = ld2(base + (size_t)i * 32768);
    decb[i] = dbase[(size_t)i * 128];
  }
  float2 S = make_float2(0.f, 0.f);
  #pragma unroll
  for (int nc = 0; nc < 64; ++nc) {
    const int sl = nc & 3;
    float2 kv = kvb[sl];
    float dec = decb[sl];
    if (nc + 4 < 64) {
      kvb[sl] = ld2(base + (size_t)(nc + 4) * 32768);
      decb[sl] = dbase[(size_t)(nc + 4) * 128];
    }
    st2(base + (size_t)nc * 32768, S);
    S.x = S.x * dec + kv.x;
    S.y = S.y * dec + kv.y;
  }
}

// ---------------------------------------------------------------- kernel D3
__global__ __launch_bounds__(256) void kD3(
    const float* __restrict__ qeG, const float* __restrict__ wkvG,
    float* __restrict__ oG) {
  __shared__ float qel[32 * 129];
  const int tid = threadIdx.x;
  const int bid = blockIdx.x;
  const int nc = bid & 63, h = (bid >> 6) & 3, b = bid >> 8;
  const int tb = b * Lc + nc * 32;
  for (int it = 0; it < 16; ++it) {
    int idx = it * 256 + tid;
    int c = idx >> 7, d = idx & 127;
    qel[c * 129 + d] = qeG[(size_t)(tb + c) * 512 + h * 128 + d];
  }
  __syncthreads();
  const int pid = tid & 63, wvx = tid >> 6;
  const int p4 = pid * 4;
  const float* Sb = wkvG + (size_t)bid * (128 * 256);
  float4 acc[8];
  #pragma unroll
  for (int q = 0; q < 8; ++q) acc[q] = make_float4(0, 0, 0, 0);
  for (int d = 0; d < 128; ++d) {
    float4 s4 = ld4(Sb + (size_t)d * 256 + p4);
    #pragma unroll
    for (int q = 0; q < 8; ++q) {
      float qv = qel[(wvx * 8 + q) * 129 + d];
      acc[q].x += s4.x * qv; acc[q].y += s4.y * qv;
      acc[q].z += s4.z * qv; acc[q].w += s4.w * qv;
    }
  }
  #pragma unroll
  for (int q = 0; q < 8; ++q) {
    float* op = oG + (size_t)(tb + wvx * 8 + q) * 1024 + h * 256 + p4;
    float4 cur = ld4(op);
    cur.x += acc[q].x; cur.y += acc[q].y; cur.z += acc[q].z; cur.w += acc[q].w;
    st4(op, cur);
  }
}

// ---------------------------------------------------------------- kernel E
__global__ __launch_bounds__(256) void kE(
    const float* __restrict__ oG, const u16* __restrict__ gG,
    const float* __restrict__ gn_w, const float* __restrict__ gn_b,
    u16* __restrict__ gate) {
  const int t = blockIdx.x;
  const int h = threadIdx.x >> 6, lane = threadIdx.x & 63;
  const int p4 = lane * 4;
  const int vd = h * 256 + p4;
  float4 v = ld4(oG + (size_t)t * 1024 + vd);
  float s = v.x + v.y + v.z + v.w;
  float ss = v.x * v.x + v.y * v.y + v.z * v.z + v.w * v.w;
  for (int m = 1; m < 64; m <<= 1) {
    s += __shfl_xor(s, m, 64);
    ss += __shfl_xor(ss, m, 64);
  }
  const float mean = s * (1.f / 256.f);
  const float var = ss * (1.f / 256.f) - mean * mean;
  const float rs = rsqrtf(var + 1e-5f);
  float4 gw = ld4(gn_w + vd), gb = ld4(gn_b + vd);
  float4 on;
  on.x = (v.x - mean) * rs * gw.x + gb.x;
  on.y = (v.y - mean) * rs * gw.y + gb.y;
  on.z = (v.z - mean) * rs * gw.z + gb.z;
  on.w = (v.w - mean) * rs * gw.w + gb.w;
  ushort4 g4 = *reinterpret_cast<const ushort4*>(gG + (size_t)t * 1024 + vd);
  float gx = bf2f(g4.x), gy = bf2f(g4.y), gz = bf2f(g4.z), gw_ = bf2f(g4.w);
  float4 sw;
  sw.x = gx / (1.f + __expf(-gx));
  sw.y = gy / (1.f + __expf(-gy));
  sw.z = gz / (1.f + __expf(-gz));
  sw.w = gw_ / (1.f + __expf(-gw_));
  ushort4 ob;
  ob.x = f2bf(on.x * sw.x); ob.y = f2bf(on.y * sw.y);
  ob.z = f2bf(on.z * sw.z); ob.w = f2bf(on.w * sw.w);
  *reinterpret_cast<ushort4*>(gate + (size_t)t * 1024 + vd) = ob;
}

// ---------------------------------------------------------------- kernel F
__global__ __launch_bounds__(256) void kF(
    const u16* __restrict__ gate, const u16* __restrict__ owb,
    float* __restrict__ out) {
  __shared__ __align__(16) u16 Abuf[128 * 64];
  __shared__ __align__(16) u16 Bbuf[128 * 64];
  const int mt = blockIdx.x, nt = blockIdx.y;
  const u16* A = gate + (size_t)mt * 128 * 1024;
  const u16* W = owb + (size_t)nt * 128 * 1024;
  float* C = out + (size_t)mt * 128 * 1024 + nt * 128;
  const int tid = threadIdx.x;
  const int lane = tid & 63;
  const int wv = tid >> 6;
  const int wr = wv >> 1, wc = wv & 1;
  const int srow = wv * 32;
  f32x4 acc[4][4];
  #pragma unroll
  for (int i = 0; i < 4; ++i)
    #pragma unroll
    for (int j = 0; j < 4; ++j) acc[i][j] = {0.f, 0.f, 0.f, 0.f};
  for (int k0 = 0; k0 < 1024; k0 += 64) {
    #pragma unroll
    for (int c = 0; c < 4; ++c) {
      const int s8 = srow + c * 8;
      stage_swz(A, Abuf, s8, k0, lane);
      stage_swz(W, Bbuf, s8, k0, lane);
    }
    __syncthreads();
    #pragma unroll
    for (int kk = 0; kk < 2; ++kk) {
      const int sl = kk * 4 + (lane >> 4);
      short8 af[4], bfr[4];
      #pragma unroll
      for (int m = 0; m < 4; ++m) {
        int row = wr * 64 + m * 16 + (lane & 15);
        af[m] = read_swz(Abuf, row, sl);
      }
      #pragma unroll
      for (int j = 0; j < 4; ++j) {
        int row = wc * 64 + j * 16 + (lane & 15);
        bfr[j] = read_swz(Bbuf, row, sl);
      }
      #pragma unroll
      for (int m = 0; m < 4; ++m)
        #pragma unroll
        for (int j = 0; j < 4; ++j)
          acc[m][j] = __builtin_amdgcn_mfma_f32_16x16x32_bf16(af[m], bfr[j], acc[m][j], 0, 0, 0);
    }
    __syncthreads();
  }
  #pragma unroll
  for (int m = 0; m < 4; ++m)
    #pragma unroll
    for (int r = 0; r < 4; ++r) {
      const int row = wr * 64 + m * 16 + (lane >> 4) * 4 + r;
      #pragma unroll
      for (int j = 0; j < 4; ++j) {
        const int col = wc * 64 + j * 16 + (lane & 15);
        C[(size_t)row * 1024 + col] = acc[m][j][r];
      }
    }
}

}  // namespace

extern "C" void kernel_launch(void* const* d_in, const int* in_sizes, int n_in,
                              void* d_out, int out_size, void* d_ws, size_t ws_size,
                              hipStream_t stream) {
  (void)in_sizes; (void)n_in; (void)out_size;
  if (ws_size < WS_NEED) return;

  const float* x      = (const float*)d_in[0];
  const float* x0_mu  = (const float*)d_in[1];
  const float* x0_w   = (const float*)d_in[2];
  const float* x2_w   = (const float*)d_in[3];
  const float* x_bias = (const float*)d_in[4];
  const float* r_w    = (const float*)d_in[5];
  const float* w_w1   = (const float*)d_in[6];
  const float* w_w2   = (const float*)d_in[7];
  const float* w_b2   = (const float*)d_in[8];
  const float* k_w    = (const float*)d_in[9];
  const float* v_w    = (const float*)d_in[10];
  const float* g_w    = (const float*)d_in[11];
  const float* bonus  = (const float*)d_in[12];
  const float* gn_w   = (const float*)d_in[13];
  const float* gn_b   = (const float*)d_in[14];
  const float* o_w    = (const float*)d_in[15];
  float* out = (float*)d_out;
  char* ws = (char*)d_ws;

  float* wkvG   = (float*)(ws + OFF_WKV);
  float* xm0    = (float*)(ws + OFF_XM0);
  float* delta  = (float*)(ws + OFF_DELTA);
  float* t160   = (float*)(ws + OFF_T160);
  float* xmw    = (float*)(ws + OFF_XMW);
  float* yw     = (float*)(ws + OFF_YW);
  u16*   x0whi  = (u16*)(ws + OFF_X0WHI);
  u16*   x0wlo  = (u16*)(ws + OFF_X0WLO);
  u16*   xm0hi  = (u16*)(ws + OFF_XM0HI);
  u16*   xm0lo  = (u16*)(ws + OFF_XM0LO);
  u16*   xmhi   = (u16*)(ws + OFF_XMHI);
  float* wfin   = (float*)(ws + OFF_WFIN);
  u16*   gate   = (u16*)(ws + OFF_GATE);
  u16*   xmlo   = (u16*)(ws + OFF_XMLO);
  float* qeG    = (float*)(ws + OFF_QE);
  float* oG     = (float*)(ws + OFF_OO);
  u16*   Whi    = (u16*)(ws + OFF_WHI);
  u16*   Wlo    = (u16*)(ws + OFF_WLO);
  float* decayG = (float*)(ws + OFF_DECAY);
  u16*   owb    = (u16*)(ws + OFF_OWB);
  float* rG     = (float*)(ws + OFF_RG);
  float* kG     = (float*)(ws + OFF_KG);
  float* vG     = (float*)(ws + OFF_VG);
  u16*   gG     = (u16*)(ws + OFF_GG);

  const size_t ldsD1 = (size_t)(8192 + 4224 + 4224 + 1056 + 32) * 4;  // 70,912 B

  kW   <<<dim3(4256),        dim3(256), 0, stream>>>(r_w, k_w, v_w, g_w, o_w, x0_w,
                                                     Whi, Wlo, owb, x0whi, x0wlo);
  kA1  <<<dim3(4096),        dim3(256), 0, stream>>>(x, x0_mu, xm0, delta, xm0hi, xm0lo);
  kA2f <<<dim3(32, 2),       dim3(256), 0, stream>>>(xm0hi, xm0lo, x0whi, x0wlo, t160);
  kA2m5<<<dim3(64, 16, 5),   dim3(256), 0, stream>>>(t160, x2_w, x_bias, xm0, delta,
                                                     x0_mu, xmhi, xmlo, xmw);
  kWL  <<<dim3(128),         dim3(256), 0, stream>>>(xmw, w_w1, yw);
  kB   <<<dim3(32, 24),      dim3(256), 0, stream>>>(xmhi, xmlo, Whi, Wlo, rG, kG, vG, gG);
  kC   <<<dim3(128, 2),      dim3(256), 0, stream>>>(yw, w_w2, w_b2, wfin);
  kD1  <<<dim3(512),         dim3(512), ldsD1, stream>>>(rG, kG, vG, wfin, bonus,
                                                         wkvG, decayG, qeG, oG);
  kD2  <<<dim3(512),         dim3(256), 0, stream>>>(wkvG, decayG);
  kD3  <<<dim3(512),         dim3(256), 0, stream>>>(qeG, wkvG, oG);
  kE   <<<dim3(4096),        dim3(256), 0, stream>>>(oG, gG, gn_w, gn_b, gate);
  kF   <<<dim3(32, 8),       dim3(256), 0, stream>>>(gate, owb, out);
}